// Round 1
// baseline (2054.911 us; speedup 1.0000x reference)
//
#include <hip/hip_runtime.h>

// RetNet block fp32 baseline.
// Workspace requirement: 29,360,128 floats = 117,440,512 bytes.

constexpr int S_LEN = 2048;
constexpr int HID   = 1024;
constexpr int NH    = 16;
constexpr int HD    = 64;
constexpr int BATCH = 2;
constexpr float EPS = 1e-5f;

// ---------------- reductions ----------------
__device__ __forceinline__ void block_reduce2(float& s, float& ss) {
  #pragma unroll
  for (int o = 32; o > 0; o >>= 1) {
    s  += __shfl_down(s, o, 64);
    ss += __shfl_down(ss, o, 64);
  }
  __shared__ float ls[4], lss[4];
  const int lane = threadIdx.x & 63;
  const int w    = threadIdx.x >> 6;
  if (lane == 0) { ls[w] = s; lss[w] = ss; }
  __syncthreads();
  if (threadIdx.x == 0) {
    float a = 0.f, b2 = 0.f;
    #pragma unroll
    for (int i = 0; i < 4; ++i) { a += ls[i]; b2 += lss[i]; }
    ls[0] = a; lss[0] = b2;
  }
  __syncthreads();
  s = ls[0]; ss = lss[0];
}

// ---------------- LayerNorm (one block per row of 1024) ----------------
__global__ __launch_bounds__(256) void ln_kernel(const float* __restrict__ x,
    const float* __restrict__ w, const float* __restrict__ b, float* __restrict__ out) {
  const int row = blockIdx.x;
  const int t   = threadIdx.x;
  const float4 v = reinterpret_cast<const float4*>(x + (size_t)row * HID)[t];
  float s  = v.x + v.y + v.z + v.w;
  float ss = v.x*v.x + v.y*v.y + v.z*v.z + v.w*v.w;
  block_reduce2(s, ss);
  const float mean = s * (1.f / HID);
  const float var  = ss * (1.f / HID) - mean * mean;
  const float rstd = rsqrtf(var + EPS);
  const float4 wv = reinterpret_cast<const float4*>(w)[t];
  const float4 bv = reinterpret_cast<const float4*>(b)[t];
  float4 o;
  o.x = (v.x - mean) * rstd * wv.x + bv.x;
  o.y = (v.y - mean) * rstd * wv.y + bv.y;
  o.z = (v.z - mean) * rstd * wv.z + bv.z;
  o.w = (v.w - mean) * rstd * wv.w + bv.w;
  reinterpret_cast<float4*>(out + (size_t)row * HID)[t] = o;
}

// ---------------- epilogue helpers ----------------
__device__ __forceinline__ float mishf(float v) {
  return v * tanhf(log1pf(expf(v)));
}
__device__ __forceinline__ float geluf(float v) {
  return 0.5f * v * (1.f + erff(v * 0.7071067811865475f));
}

// ---------------- tiled fp32 GEMM: C = epi(A[M,K] @ B[K,N]) ----------------
// BM=BN=64, BK=16, 256 threads, 4x4 microtile per thread.
// EPI: 0 none, 1 mish, 2 +res, 3 gelu(acc+bias), 4 acc+bias+res
template <int EPI>
__global__ __launch_bounds__(256) void gemm_kernel(
    const float* __restrict__ A, const float* __restrict__ Bm,
    const float* __restrict__ bias, const float* __restrict__ res,
    float* __restrict__ C, int N, int K) {
  __shared__ float As[64][17];
  __shared__ float Bs[16][65];
  const int tid = threadIdx.x;
  const int tr4 = (tid >> 4) << 2;
  const int tc4 = (tid & 15) << 2;
  const int rowBase = blockIdx.y << 6;
  const int colBase = blockIdx.x << 6;
  float acc[4][4] = {};
  const int arow = tid >> 2, ac4 = (tid & 3) << 2;
  const int brow = tid >> 4, bc4 = (tid & 15) << 2;
  for (int k0 = 0; k0 < K; k0 += 16) {
    const float4 av = *reinterpret_cast<const float4*>(A + (size_t)(rowBase + arow) * K + k0 + ac4);
    As[arow][ac4+0] = av.x; As[arow][ac4+1] = av.y; As[arow][ac4+2] = av.z; As[arow][ac4+3] = av.w;
    const float4 bv = *reinterpret_cast<const float4*>(Bm + (size_t)(k0 + brow) * N + colBase + bc4);
    Bs[brow][bc4+0] = bv.x; Bs[brow][bc4+1] = bv.y; Bs[brow][bc4+2] = bv.z; Bs[brow][bc4+3] = bv.w;
    __syncthreads();
    #pragma unroll
    for (int kk = 0; kk < 16; ++kk) {
      float a[4], b[4];
      #pragma unroll
      for (int i = 0; i < 4; ++i) a[i] = As[tr4 + i][kk];
      #pragma unroll
      for (int j = 0; j < 4; ++j) b[j] = Bs[kk][tc4 + j];
      #pragma unroll
      for (int i = 0; i < 4; ++i)
        #pragma unroll
        for (int j = 0; j < 4; ++j)
          acc[i][j] = fmaf(a[i], b[j], acc[i][j]);
    }
    __syncthreads();
  }
  #pragma unroll
  for (int i = 0; i < 4; ++i) {
    const int r  = rowBase + tr4 + i;
    const int c0 = colBase + tc4;
    float o[4];
    #pragma unroll
    for (int j = 0; j < 4; ++j) {
      float v = acc[i][j];
      if constexpr (EPI == 1) v = mishf(v);
      if constexpr (EPI == 2) v = v + res[(size_t)r * N + c0 + j];
      if constexpr (EPI == 3) v = geluf(v + bias[c0 + j]);
      if constexpr (EPI == 4) v = v + bias[c0 + j] + res[(size_t)r * N + c0 + j];
      o[j] = v;
    }
    float4 ov; ov.x = o[0]; ov.y = o[1]; ov.z = o[2]; ov.w = o[3];
    *reinterpret_cast<float4*>(C + (size_t)r * N + c0) = ov;
  }
}

// ---------------- in-place xPos rotary on qkv (layout (b,s) x 3072 = 16 heads x 192) ----------------
__global__ __launch_bounds__(256) void rotary_kernel(float* __restrict__ qkv) {
  const int g = blockIdx.x * 256 + threadIdx.x;   // over B*S*NH*16 pairs
  const int i = g & 15;
  const int h = (g >> 4) & 15;
  const int s = (g >> 8) & (S_LEN - 1);
  const int b = g >> 19;
  const float t = (float)s;
  // inv_freq = theta^(-2i/32); log2(10000) = 13.2877123795...
  const float invf = exp2f(-((float)(2 * i) * (1.f / 32.f)) * 13.287712379549449f);
  const float ang = t * invf;
  const float sn = sinf(ang), cs = cosf(ang);
  const float p = (t - 1024.f) * (1.f / 512.f);   // (t - S//2)/SCALE_BASE
  const int j0 = 2 * i, j1 = 2 * i + 1;
  const float sv0 = (2.f * (float)(j0 & 15) + 12.8f) * (1.f / 44.8f);
  const float sv1 = (2.f * (float)(j1 & 15) + 12.8f) * (1.f / 44.8f);
  const float l0 = log2f(sv0) * p;
  const float l1 = log2f(sv1) * p;
  const float scq0 = exp2f(l0),  scq1 = exp2f(l1);
  const float sck0 = exp2f(-l0), sck1 = exp2f(-l1);
  float* base = qkv + (size_t)(b * S_LEN + s) * 3072 + h * 192;
  const float q0 = base[j0], q1 = base[j1];
  base[j0] = (q0 * cs - q1 * sn) * scq0;
  base[j1] = (q1 * cs + q0 * sn) * scq1;
  const float k0 = base[64 + j0], k1 = base[64 + j1];
  base[64 + j0] = (k0 * cs - k1 * sn) * sck0;
  base[64 + j1] = (k1 * cs + k0 * sn) * sck1;
}

// ---------------- retention: ret = (Q K^T * gamma^(s-t) [s>=t]) V ----------------
__device__ __forceinline__ void load_tile(const float* __restrict__ g, float (*dst)[65], int tid) {
  #pragma unroll
  for (int p = 0; p < 4; ++p) {
    const int idx = tid + (p << 8);
    const int row = idx >> 4;
    const int c4  = (idx & 15) << 2;
    const float4 v = *reinterpret_cast<const float4*>(g + (size_t)row * 3072 + c4);
    dst[row][c4+0] = v.x; dst[row][c4+1] = v.y; dst[row][c4+2] = v.z; dst[row][c4+3] = v.w;
  }
}

__global__ __launch_bounds__(256) void retention_kernel(const float* __restrict__ qkv,
                                                        float* __restrict__ ret) {
  const int sblk = blockIdx.x;  // 0..31
  const int h    = blockIdx.y;
  const int b    = blockIdx.z;
  const int tid  = threadIdx.x;
  const int tr4  = (tid >> 4) << 2;
  const int tc4  = (tid & 15) << 2;
  const int sBase = sblk << 6;
  const float gamma = 1.f - exp2f(-5.f - (float)h);
  const float l2g   = log2f(gamma);   // negative
  __shared__ float Qs[64][65];
  __shared__ float KSs[64][65];  // K tile, then reused for decayed scores S^
  __shared__ float Vs[64][65];
  float acc[4][4] = {};
  load_tile(qkv + (size_t)(b * S_LEN + sBase) * 3072 + h * 192, Qs, tid);
  for (int tblk = 0; tblk <= sblk; ++tblk) {
    const int tBase = tblk << 6;
    const int nmin  = sBase - tBase - 63;  // smallest decay exponent in tile
    if (nmin > 0 && (float)nmin * l2g < -45.f) continue;  // gamma^n < 2^-45: negligible
    const float* kb = qkv + (size_t)(b * S_LEN + tBase) * 3072 + h * 192 + 64;
    load_tile(kb,      KSs, tid);
    load_tile(kb + 64, Vs,  tid);
    __syncthreads();
    float sc[4][4] = {};
    #pragma unroll 8
    for (int d = 0; d < 64; ++d) {
      float a[4], bb[4];
      #pragma unroll
      for (int i = 0; i < 4; ++i) a[i] = Qs[tr4 + i][d];
      #pragma unroll
      for (int j = 0; j < 4; ++j) bb[j] = KSs[tc4 + j][d];
      #pragma unroll
      for (int i = 0; i < 4; ++i)
        #pragma unroll
        for (int j = 0; j < 4; ++j)
          sc[i][j] = fmaf(a[i], bb[j], sc[i][j]);
    }
    __syncthreads();
    #pragma unroll
    for (int i = 0; i < 4; ++i)
      #pragma unroll
      for (int j = 0; j < 4; ++j) {
        const int n = (sBase + tr4 + i) - (tBase + tc4 + j);
        const float dec = (n < 0) ? 0.f : exp2f((float)n * l2g);
        KSs[tr4 + i][tc4 + j] = sc[i][j] * dec;
      }
    __syncthreads();
    #pragma unroll 8
    for (int t = 0; t < 64; ++t) {
      float a[4], bb[4];
      #pragma unroll
      for (int i = 0; i < 4; ++i) a[i] = KSs[tr4 + i][t];
      #pragma unroll
      for (int j = 0; j < 4; ++j) bb[j] = Vs[t][tc4 + j];
      #pragma unroll
      for (int i = 0; i < 4; ++i)
        #pragma unroll
        for (int j = 0; j < 4; ++j)
          acc[i][j] = fmaf(a[i], bb[j], acc[i][j]);
    }
    __syncthreads();
  }
  float* ob = ret + (size_t)((b * NH + h) * S_LEN + sBase) * HD;
  #pragma unroll
  for (int i = 0; i < 4; ++i) {
    float4 o; o.x = acc[i][0]; o.y = acc[i][1]; o.z = acc[i][2]; o.w = acc[i][3];
    *reinterpret_cast<float4*>(ob + (size_t)(tr4 + i) * HD + tc4) = o;
  }
}

// ---------------- group norm over (S, D) per (b,h), fused with mish-gate multiply + head re-transpose ----------------
__global__ __launch_bounds__(256) void gn_kernel(const float* __restrict__ ret,
    const float* __restrict__ gm, const float* __restrict__ gn_w, const float* __restrict__ gn_b,
    float* __restrict__ yin) {
  const int bh = blockIdx.x;
  const int b = bh >> 4, h = bh & 15;
  const float4* r4 = reinterpret_cast<const float4*>(ret + (size_t)bh * (S_LEN * HD));
  float s = 0.f, ss = 0.f;
  for (int i = threadIdx.x; i < S_LEN * HD / 4; i += 256) {
    const float4 v = r4[i];
    s  += v.x + v.y + v.z + v.w;
    ss += v.x*v.x + v.y*v.y + v.z*v.z + v.w*v.w;
  }
  block_reduce2(s, ss);
  const float inv  = 1.f / (float)(S_LEN * HD);
  const float mean = s * inv;
  const float var  = ss * inv - mean * mean;
  const float rstd = rsqrtf(var + EPS);
  const float a = gn_w[h] * rstd;
  const float c = gn_b[h] - mean * a;
  for (int i = threadIdx.x; i < S_LEN * HD / 4; i += 256) {
    const float4 v = r4[i];
    const int e    = i << 2;
    const int srow = e >> 6;
    const int d    = e & 63;
    const size_t oidx = (size_t)(b * S_LEN + srow) * HID + h * HD + d;
    const float4 g = *reinterpret_cast<const float4*>(gm + oidx);
    float4 o;
    o.x = (v.x * a + c) * g.x;
    o.y = (v.y * a + c) * g.y;
    o.z = (v.z * a + c) * g.z;
    o.w = (v.w * a + c) * g.w;
    *reinterpret_cast<float4*>(yin + oidx) = o;
  }
}

// ---------------- launcher ----------------
extern "C" void kernel_launch(void* const* d_in, const int* in_sizes, int n_in,
                              void* d_out, int out_size, void* d_ws, size_t ws_size,
                              hipStream_t stream) {
  const float* x     = (const float*)d_in[0];
  const float* ln1_w = (const float*)d_in[1];
  const float* ln1_b = (const float*)d_in[2];
  const float* wqkv  = (const float*)d_in[3];
  const float* wg    = (const float*)d_in[4];
  const float* wo    = (const float*)d_in[5];
  const float* gn_w  = (const float*)d_in[6];
  const float* gn_b  = (const float*)d_in[7];
  const float* ln2_w = (const float*)d_in[8];
  const float* ln2_b = (const float*)d_in[9];
  const float* w1    = (const float*)d_in[10];
  const float* w1_b  = (const float*)d_in[11];
  const float* w2    = (const float*)d_in[12];
  const float* w2_b  = (const float*)d_in[13];

  float* ws = (float*)d_ws;
  // layout (floats):
  float* h     = ws;                 // 4,194,304   [ln1 -> gemm_g]
  float* qkv   = ws + 4194304;       // 12,582,912  [gemm_qkv -> retention]
  float* ret   = ws + 16777216;      // 4,194,304   [retention -> gn]
  float* gmish = ws + 20971520;      // 4,194,304   [gemm_g -> gn]
  float* y     = ws + 25165824;      // 4,194,304   [gemm_wo -> end]
  float* yin   = qkv;                // reuse (qkv dead after retention)
  float* z     = qkv + 4194304;
  float* f     = qkv + 8388608;
  float* out   = (float*)d_out;

  ln_kernel<<<BATCH * S_LEN, 256, 0, stream>>>(x, ln1_w, ln1_b, h);
  gemm_kernel<0><<<dim3(3072 / 64, 4096 / 64), 256, 0, stream>>>(h, wqkv, nullptr, nullptr, qkv, 3072, 1024);
  rotary_kernel<<<(BATCH * S_LEN * NH * 16) / 256, 256, 0, stream>>>(qkv);
  gemm_kernel<1><<<dim3(1024 / 64, 4096 / 64), 256, 0, stream>>>(h, wg, nullptr, nullptr, gmish, 1024, 1024);
  retention_kernel<<<dim3(S_LEN / 64, NH, BATCH), 256, 0, stream>>>(qkv, ret);
  gn_kernel<<<BATCH * NH, 256, 0, stream>>>(ret, gmish, gn_w, gn_b, yin);
  gemm_kernel<2><<<dim3(1024 / 64, 4096 / 64), 256, 0, stream>>>(yin, wo, nullptr, x, y, 1024, 1024);
  ln_kernel<<<BATCH * S_LEN, 256, 0, stream>>>(y, ln2_w, ln2_b, z);
  gemm_kernel<3><<<dim3(1024 / 64, 4096 / 64), 256, 0, stream>>>(z, w1, w1_b, nullptr, f, 1024, 1024);
  gemm_kernel<4><<<dim3(1024 / 64, 4096 / 64), 256, 0, stream>>>(f, w2, w2_b, y, out, 1024, 1024);
}

// Round 4
// 1147.778 us; speedup vs baseline: 1.7903x; 1.7903x over previous
//
#include <hip/hip_runtime.h>

// RetNet block: bf16x3 MFMA GEMMs + fp32 retention.
// Workspace usage: 113,246,208 bytes.

constexpr int S_LEN = 2048;
constexpr int HID   = 1024;
constexpr int NH    = 16;
constexpr int HD    = 64;
constexpr int BATCH = 2;
constexpr float EPS = 1e-5f;

using short8 = __attribute__((ext_vector_type(8))) short;
using f32x4  = __attribute__((ext_vector_type(4))) float;

// ---------------- bf16 split helpers ----------------
__device__ __forceinline__ ushort bf16rne(float x) {
  unsigned u = __float_as_uint(x);
  unsigned r = (u + 0x7fffu + ((u >> 16) & 1u)) >> 16;
  return (ushort)r;
}
__device__ __forceinline__ void split2(float x, ushort& hi, ushort& lo) {
  hi = bf16rne(x);
  float hf = __uint_as_float((unsigned)hi << 16);
  lo = bf16rne(x - hf);
}

// ---------------- reductions ----------------
__device__ __forceinline__ void block_reduce2(float& s, float& ss) {
  #pragma unroll
  for (int o = 32; o > 0; o >>= 1) {
    s  += __shfl_down(s, o, 64);
    ss += __shfl_down(ss, o, 64);
  }
  __shared__ float ls[4], lss[4];
  const int lane = threadIdx.x & 63;
  const int w    = threadIdx.x >> 6;
  if (lane == 0) { ls[w] = s; lss[w] = ss; }
  __syncthreads();
  if (threadIdx.x == 0) {
    float a = 0.f, b2 = 0.f;
    #pragma unroll
    for (int i = 0; i < 4; ++i) { a += ls[i]; b2 += lss[i]; }
    ls[0] = a; lss[0] = b2;
  }
  __syncthreads();
  s = ls[0]; ss = lss[0];
}

// ---------------- LayerNorm -> bf16 hi/lo ----------------
__global__ __launch_bounds__(256) void ln_split_kernel(const float* __restrict__ x,
    const float* __restrict__ w, const float* __restrict__ b,
    ushort* __restrict__ oh, ushort* __restrict__ ol) {
  const int row = blockIdx.x;
  const int t   = threadIdx.x;
  const float4 v = reinterpret_cast<const float4*>(x + (size_t)row * HID)[t];
  float s  = v.x + v.y + v.z + v.w;
  float ss = v.x*v.x + v.y*v.y + v.z*v.z + v.w*v.w;
  block_reduce2(s, ss);
  const float mean = s * (1.f / HID);
  const float var  = ss * (1.f / HID) - mean * mean;
  const float rstd = rsqrtf(var + EPS);
  const float4 wv = reinterpret_cast<const float4*>(w)[t];
  const float4 bv = reinterpret_cast<const float4*>(b)[t];
  float o[4];
  o[0] = (v.x - mean) * rstd * wv.x + bv.x;
  o[1] = (v.y - mean) * rstd * wv.y + bv.y;
  o[2] = (v.z - mean) * rstd * wv.z + bv.z;
  o[3] = (v.w - mean) * rstd * wv.w + bv.w;
  ushort4 hv, lv;
  split2(o[0], hv.x, lv.x); split2(o[1], hv.y, lv.y);
  split2(o[2], hv.z, lv.z); split2(o[3], hv.w, lv.w);
  *reinterpret_cast<ushort4*>(oh + (size_t)row * HID + t * 4) = hv;
  *reinterpret_cast<ushort4*>(ol + (size_t)row * HID + t * 4) = lv;
}

// ---------------- weight transpose + split: W[K][N] -> T[N][K] hi/lo ----------------
__global__ __launch_bounds__(256) void wsplit_kernel(const float* __restrict__ W,
    ushort* __restrict__ Th, ushort* __restrict__ Tl, int N) {
  __shared__ float tile[32][33];
  const int k0 = blockIdx.y * 32;
  const int n0 = blockIdx.x * 32;
  const int tx = threadIdx.x & 31, ty = threadIdx.x >> 5;  // ty 0..7
  #pragma unroll
  for (int r = 0; r < 4; ++r)
    tile[ty + 8*r][tx] = W[(size_t)(k0 + ty + 8*r) * N + n0 + tx];
  __syncthreads();
  #pragma unroll
  for (int r = 0; r < 4; ++r) {
    const int n = ty + 8*r;
    const float v = tile[tx][n];   // = W[k0+tx][n0+n]
    ushort hi, lo; split2(v, hi, lo);
    Th[(size_t)(n0 + n) * 1024 + k0 + tx] = hi;
    Tl[(size_t)(n0 + n) * 1024 + k0 + tx] = lo;
  }
}

// ---------------- epilogue helpers ----------------
__device__ __forceinline__ float mishf(float v) {
  return v * tanhf(log1pf(expf(v)));
}
__device__ __forceinline__ float geluf(float v) {
  return 0.5f * v * (1.f + erff(v * 0.7071067811865475f));
}

// ---------------- bf16x3 MFMA GEMM ----------------
// C[M,N] = epi(A[M,K] @ B[K,N]) with A given as row-major hi/lo bf16 [M][K],
// B given TRANSPOSED as [N][K] hi/lo bf16. 128x128 tile, BK=64, 4 waves (2x2).
// EPI: 0 none, 1 mish, 2 +res, 3 gelu(acc+bias)->split out, 4 acc+bias+res
template <int EPI>
__global__ __launch_bounds__(256, 2) void gemm_mfma(
    const ushort* __restrict__ Ah, const ushort* __restrict__ Al,
    const ushort* __restrict__ Bh, const ushort* __restrict__ Bl,
    const float* __restrict__ bias, const float* __restrict__ res,
    float* __restrict__ C, ushort* __restrict__ Ch, ushort* __restrict__ Cl,
    int N, int K) {
  __shared__ ushort sA[2][128 * 64];
  __shared__ ushort sB[2][128 * 64];
  const int tid  = threadIdx.x;
  const int lane = tid & 63;
  const int w    = tid >> 6;
  const int wm   = w >> 1, wn = w & 1;
  const int rowBase = blockIdx.y * 128;
  const int colBase = blockIdx.x * 128;

  f32x4 acc[4][4] = {};

  const int l8   = lane >> 3;            // row within 8-row chunk
  const int kswz = ((lane & 7) * 16) ^ (l8 << 4);  // pre-swizzled source byte off

  for (int k0 = 0; k0 < K; k0 += 64) {
    __syncthreads();
    // stage 4 tiles: each wave stages rows [w*32, w*32+32) of each
    #pragma unroll
    for (int c = 0; c < 4; ++c) {
      const int row = w * 32 + c * 8;
      const char* gah = (const char*)(Ah + (size_t)(rowBase + row + l8) * K + k0) + kswz;
      const char* gal = (const char*)(Al + (size_t)(rowBase + row + l8) * K + k0) + kswz;
      const char* gbh = (const char*)(Bh + (size_t)(colBase + row + l8) * K + k0) + kswz;
      const char* gbl = (const char*)(Bl + (size_t)(colBase + row + l8) * K + k0) + kswz;
      __builtin_amdgcn_global_load_lds((const __attribute__((address_space(1))) void*)gah,
          (__attribute__((address_space(3))) void*)((char*)sA[0] + row * 128), 16, 0, 0);
      __builtin_amdgcn_global_load_lds((const __attribute__((address_space(1))) void*)gal,
          (__attribute__((address_space(3))) void*)((char*)sA[1] + row * 128), 16, 0, 0);
      __builtin_amdgcn_global_load_lds((const __attribute__((address_space(1))) void*)gbh,
          (__attribute__((address_space(3))) void*)((char*)sB[0] + row * 128), 16, 0, 0);
      __builtin_amdgcn_global_load_lds((const __attribute__((address_space(1))) void*)gbl,
          (__attribute__((address_space(3))) void*)((char*)sB[1] + row * 128), 16, 0, 0);
    }
    __syncthreads();
    #pragma unroll
    for (int kk = 0; kk < 2; ++kk) {
      const int kb = kk * 64 + ((lane >> 4) << 4);  // byte offset of 8 bf16 within row
      short8 ah[4], al[4], bh[4], bl[4];
      #pragma unroll
      for (int i = 0; i < 4; ++i) {
        const int row = wm * 64 + i * 16 + (lane & 15);
        const int off = row * 128 + (kb ^ ((row & 7) << 4));
        ah[i] = *(const short8*)((const char*)sA[0] + off);
        al[i] = *(const short8*)((const char*)sA[1] + off);
      }
      #pragma unroll
      for (int j = 0; j < 4; ++j) {
        const int row = wn * 64 + j * 16 + (lane & 15);
        const int off = row * 128 + (kb ^ ((row & 7) << 4));
        bh[j] = *(const short8*)((const char*)sB[0] + off);
        bl[j] = *(const short8*)((const char*)sB[1] + off);
      }
      #pragma unroll
      for (int i = 0; i < 4; ++i)
        #pragma unroll
        for (int j = 0; j < 4; ++j) {
          acc[i][j] = __builtin_amdgcn_mfma_f32_16x16x32_bf16(ah[i], bh[j], acc[i][j], 0, 0, 0);
          acc[i][j] = __builtin_amdgcn_mfma_f32_16x16x32_bf16(ah[i], bl[j], acc[i][j], 0, 0, 0);
          acc[i][j] = __builtin_amdgcn_mfma_f32_16x16x32_bf16(al[i], bh[j], acc[i][j], 0, 0, 0);
        }
    }
  }

  // epilogue: C/D layout col=lane&15, row=(lane>>4)*4+reg
  const int cRow = rowBase + wm * 64 + ((lane >> 4) << 2);
  const int cCol = colBase + wn * 64 + (lane & 15);
  #pragma unroll
  for (int i = 0; i < 4; ++i)
    #pragma unroll
    for (int j = 0; j < 4; ++j) {
      const int gc = cCol + j * 16;
      #pragma unroll
      for (int r = 0; r < 4; ++r) {
        const int gr = cRow + i * 16 + r;
        float v = acc[i][j][r];
        if constexpr (EPI == 1) v = mishf(v);
        if constexpr (EPI == 2) v += res[(size_t)gr * N + gc];
        if constexpr (EPI == 3) v = geluf(v + bias[gc]);
        if constexpr (EPI == 4) v += bias[gc] + res[(size_t)gr * N + gc];
        if constexpr (EPI == 3) {
          ushort hi, lo; split2(v, hi, lo);
          Ch[(size_t)gr * N + gc] = hi;
          Cl[(size_t)gr * N + gc] = lo;
        } else {
          C[(size_t)gr * N + gc] = v;
        }
      }
    }
}

// ---------------- in-place xPos rotary on qkv ----------------
__global__ __launch_bounds__(256) void rotary_kernel(float* __restrict__ qkv) {
  const int g = blockIdx.x * 256 + threadIdx.x;
  const int i = g & 15;
  const int h = (g >> 4) & 15;
  const int s = (g >> 8) & (S_LEN - 1);
  const int b = g >> 19;
  const float t = (float)s;
  const float invf = exp2f(-((float)(2 * i) * (1.f / 32.f)) * 13.287712379549449f);
  const float ang = t * invf;
  const float sn = sinf(ang), cs = cosf(ang);
  const float p = (t - 1024.f) * (1.f / 512.f);
  const int j0 = 2 * i, j1 = 2 * i + 1;
  const float sv0 = (2.f * (float)(j0 & 15) + 12.8f) * (1.f / 44.8f);
  const float sv1 = (2.f * (float)(j1 & 15) + 12.8f) * (1.f / 44.8f);
  const float l0 = log2f(sv0) * p;
  const float l1 = log2f(sv1) * p;
  const float scq0 = exp2f(l0),  scq1 = exp2f(l1);
  const float sck0 = exp2f(-l0), sck1 = exp2f(-l1);
  float* base = qkv + (size_t)(b * S_LEN + s) * 3072 + h * 192;
  const float q0 = base[j0], q1 = base[j1];
  base[j0] = (q0 * cs - q1 * sn) * scq0;
  base[j1] = (q1 * cs + q0 * sn) * scq1;
  const float k0 = base[64 + j0], k1 = base[64 + j1];
  base[64 + j0] = (k0 * cs - k1 * sn) * sck0;
  base[64 + j1] = (k1 * cs + k0 * sn) * sck1;
}

// ---------------- retention (fp32) ----------------
__device__ __forceinline__ void load_tile(const float* __restrict__ g, float (*dst)[65], int tid) {
  #pragma unroll
  for (int p = 0; p < 4; ++p) {
    const int idx = tid + (p << 8);
    const int row = idx >> 4;
    const int c4  = (idx & 15) << 2;
    const float4 v = *reinterpret_cast<const float4*>(g + (size_t)row * 3072 + c4);
    dst[row][c4+0] = v.x; dst[row][c4+1] = v.y; dst[row][c4+2] = v.z; dst[row][c4+3] = v.w;
  }
}

__global__ __launch_bounds__(256) void retention_kernel(const float* __restrict__ qkv,
                                                        float* __restrict__ ret) {
  const int sblk = blockIdx.x;
  const int h    = blockIdx.y;
  const int b    = blockIdx.z;
  const int tid  = threadIdx.x;
  const int tr4  = (tid >> 4) << 2;
  const int tc4  = (tid & 15) << 2;
  const int sBase = sblk << 6;
  const float gamma = 1.f - exp2f(-5.f - (float)h);
  const float l2g   = log2f(gamma);
  __shared__ float Qs[64][65];
  __shared__ float KSs[64][65];
  __shared__ float Vs[64][65];
  float acc[4][4] = {};
  load_tile(qkv + (size_t)(b * S_LEN + sBase) * 3072 + h * 192, Qs, tid);
  for (int tblk = 0; tblk <= sblk; ++tblk) {
    const int tBase = tblk << 6;
    const int nmin  = sBase - tBase - 63;
    if (nmin > 0 && (float)nmin * l2g < -45.f) continue;
    const float* kb = qkv + (size_t)(b * S_LEN + tBase) * 3072 + h * 192 + 64;
    load_tile(kb,      KSs, tid);
    load_tile(kb + 64, Vs,  tid);
    __syncthreads();
    float sc[4][4] = {};
    #pragma unroll 8
    for (int d = 0; d < 64; ++d) {
      float a[4], bb[4];
      #pragma unroll
      for (int i = 0; i < 4; ++i) a[i] = Qs[tr4 + i][d];
      #pragma unroll
      for (int j = 0; j < 4; ++j) bb[j] = KSs[tc4 + j][d];
      #pragma unroll
      for (int i = 0; i < 4; ++i)
        #pragma unroll
        for (int j = 0; j < 4; ++j)
          sc[i][j] = fmaf(a[i], bb[j], sc[i][j]);
    }
    __syncthreads();
    #pragma unroll
    for (int i = 0; i < 4; ++i)
      #pragma unroll
      for (int j = 0; j < 4; ++j) {
        const int n = (sBase + tr4 + i) - (tBase + tc4 + j);
        const float dec = (n < 0) ? 0.f : exp2f((float)n * l2g);
        KSs[tr4 + i][tc4 + j] = sc[i][j] * dec;
      }
    __syncthreads();
    #pragma unroll 8
    for (int t = 0; t < 64; ++t) {
      float a[4], bb[4];
      #pragma unroll
      for (int i = 0; i < 4; ++i) a[i] = KSs[tr4 + i][t];
      #pragma unroll
      for (int j = 0; j < 4; ++j) bb[j] = Vs[t][tc4 + j];
      #pragma unroll
      for (int i = 0; i < 4; ++i)
        #pragma unroll
        for (int j = 0; j < 4; ++j)
          acc[i][j] = fmaf(a[i], bb[j], acc[i][j]);
    }
    __syncthreads();
  }
  float* ob = ret + (size_t)((b * NH + h) * S_LEN + sBase) * HD;
  #pragma unroll
  for (int i = 0; i < 4; ++i) {
    float4 o; o.x = acc[i][0]; o.y = acc[i][1]; o.z = acc[i][2]; o.w = acc[i][3];
    *reinterpret_cast<float4*>(ob + (size_t)(tr4 + i) * HD + tc4) = o;
  }
}

// ---------------- group norm + gate, emitting bf16 hi/lo ----------------
__global__ __launch_bounds__(256) void gn_kernel(const float* __restrict__ ret,
    const float* __restrict__ gm, const float* __restrict__ gn_w, const float* __restrict__ gn_b,
    ushort* __restrict__ yh, ushort* __restrict__ yl) {
  const int bh = blockIdx.x;
  const int b = bh >> 4, h = bh & 15;
  const float4* r4 = reinterpret_cast<const float4*>(ret + (size_t)bh * (S_LEN * HD));
  float s = 0.f, ss = 0.f;
  for (int i = threadIdx.x; i < S_LEN * HD / 4; i += 256) {
    const float4 v = r4[i];
    s  += v.x + v.y + v.z + v.w;
    ss += v.x*v.x + v.y*v.y + v.z*v.z + v.w*v.w;
  }
  block_reduce2(s, ss);
  const float inv  = 1.f / (float)(S_LEN * HD);
  const float mean = s * inv;
  const float var  = ss * inv - mean * mean;
  const float rstd = rsqrtf(var + EPS);
  const float a = gn_w[h] * rstd;
  const float c = gn_b[h] - mean * a;
  for (int i = threadIdx.x; i < S_LEN * HD / 4; i += 256) {
    const float4 v = r4[i];
    const int e    = i << 2;
    const int srow = e >> 6;
    const int d    = e & 63;
    const size_t oidx = (size_t)(b * S_LEN + srow) * HID + h * HD + d;
    const float4 g = *reinterpret_cast<const float4*>(gm + oidx);
    float o0 = (v.x * a + c) * g.x;
    float o1 = (v.y * a + c) * g.y;
    float o2 = (v.z * a + c) * g.z;
    float o3 = (v.w * a + c) * g.w;
    ushort4 hv, lv;
    split2(o0, hv.x, lv.x); split2(o1, hv.y, lv.y);
    split2(o2, hv.z, lv.z); split2(o3, hv.w, lv.w);
    *reinterpret_cast<ushort4*>(yh + oidx) = hv;
    *reinterpret_cast<ushort4*>(yl + oidx) = lv;
  }
}

// ---------------- launcher ----------------
extern "C" void kernel_launch(void* const* d_in, const int* in_sizes, int n_in,
                              void* d_out, int out_size, void* d_ws, size_t ws_size,
                              hipStream_t stream) {
  const float* x     = (const float*)d_in[0];
  const float* ln1_w = (const float*)d_in[1];
  const float* ln1_b = (const float*)d_in[2];
  const float* wqkv  = (const float*)d_in[3];
  const float* wg    = (const float*)d_in[4];
  const float* wo    = (const float*)d_in[5];
  const float* gn_w  = (const float*)d_in[6];
  const float* gn_b  = (const float*)d_in[7];
  const float* ln2_w = (const float*)d_in[8];
  const float* ln2_b = (const float*)d_in[9];
  const float* w1    = (const float*)d_in[10];
  const float* w1_b  = (const float*)d_in[11];
  const float* w2    = (const float*)d_in[12];
  const float* w2_b  = (const float*)d_in[13];

  char* ws = (char*)d_ws;
  // byte offsets
  ushort* wqkvT_h = (ushort*)(ws + 0);          // 6,291,456
  ushort* wqkvT_l = (ushort*)(ws + 6291456);
  ushort* wgT_h   = (ushort*)(ws + 12582912);   // 2,097,152 each below
  ushort* wgT_l   = (ushort*)(ws + 14680064);
  ushort* woT_h   = (ushort*)(ws + 16777216);
  ushort* woT_l   = (ushort*)(ws + 18874368);
  ushort* w1T_h   = (ushort*)(ws + 20971520);
  ushort* w1T_l   = (ushort*)(ws + 23068672);
  ushort* w2T_h   = (ushort*)(ws + 25165824);
  ushort* w2T_l   = (ushort*)(ws + 27262976);
  ushort* h_hi    = (ushort*)(ws + 29360128);   // 8,388,608
  ushort* h_lo    = (ushort*)(ws + 37748736);
  float*  qkv     = (float*) (ws + 46137344);   // 50,331,648
  float*  gmish   = (float*) (ws + 96468992);   // 16,777,216
  // reuse of h region after gemm<1>:
  float*  ret     = (float*) (ws + 29360128);   // 16,777,216
  // reuse of qkv region after retention:
  ushort* yin_h   = (ushort*)(ws + 46137344);
  ushort* yin_l   = (ushort*)(ws + 54525952);
  float*  y       = (float*) (ws + 62914560);   // 16,777,216
  ushort* z_h     = (ushort*)(ws + 79691776);
  ushort* z_l     = (ushort*)(ws + 88080384);
  // reuse of gmish region after gn:
  ushort* f_h     = (ushort*)(ws + 96468992);
  ushort* f_l     = (ushort*)(ws + 104857600);  // ends 113,246,208
  float*  out     = (float*)d_out;

  // weight transpose+split
  wsplit_kernel<<<dim3(3072/32, 32), 256, 0, stream>>>(wqkv, wqkvT_h, wqkvT_l, 3072);
  wsplit_kernel<<<dim3(1024/32, 32), 256, 0, stream>>>(wg, wgT_h, wgT_l, 1024);
  wsplit_kernel<<<dim3(1024/32, 32), 256, 0, stream>>>(wo, woT_h, woT_l, 1024);
  wsplit_kernel<<<dim3(1024/32, 32), 256, 0, stream>>>(w1, w1T_h, w1T_l, 1024);
  wsplit_kernel<<<dim3(1024/32, 32), 256, 0, stream>>>(w2, w2T_h, w2T_l, 1024);

  ln_split_kernel<<<BATCH * S_LEN, 256, 0, stream>>>(x, ln1_w, ln1_b, h_hi, h_lo);
  gemm_mfma<0><<<dim3(3072/128, 4096/128), 256, 0, stream>>>(h_hi, h_lo, wqkvT_h, wqkvT_l,
      nullptr, nullptr, qkv, nullptr, nullptr, 3072, 1024);
  rotary_kernel<<<(BATCH * S_LEN * NH * 16) / 256, 256, 0, stream>>>(qkv);
  gemm_mfma<1><<<dim3(1024/128, 4096/128), 256, 0, stream>>>(h_hi, h_lo, wgT_h, wgT_l,
      nullptr, nullptr, gmish, nullptr, nullptr, 1024, 1024);
  retention_kernel<<<dim3(S_LEN/64, NH, BATCH), 256, 0, stream>>>(qkv, ret);
  gn_kernel<<<BATCH * NH, 256, 0, stream>>>(ret, gmish, gn_w, gn_b, yin_h, yin_l);
  gemm_mfma<2><<<dim3(1024/128, 4096/128), 256, 0, stream>>>(yin_h, yin_l, woT_h, woT_l,
      nullptr, x, y, nullptr, nullptr, 1024, 1024);
  ln_split_kernel<<<BATCH * S_LEN, 256, 0, stream>>>(y, ln2_w, ln2_b, z_h, z_l);
  gemm_mfma<3><<<dim3(1024/128, 4096/128), 256, 0, stream>>>(z_h, z_l, w1T_h, w1T_l,
      w1_b, nullptr, nullptr, f_h, f_l, 1024, 1024);
  gemm_mfma<4><<<dim3(1024/128, 4096/128), 256, 0, stream>>>(f_h, f_l, w2T_h, w2T_l,
      w2_b, y, out, nullptr, nullptr, 1024, 1024);
}

// Round 5
// 614.539 us; speedup vs baseline: 3.3438x; 1.8677x over previous
//
#include <hip/hip_runtime.h>

// RetNet block: bf16x3 MFMA GEMMs + bf16x3 MFMA retention (fused rotary in qkv GEMM).
// Workspace usage: 113,770,496 bytes.

constexpr int S_LEN = 2048;
constexpr int HID   = 1024;
constexpr int NH    = 16;
constexpr int HD    = 64;
constexpr int BATCH = 2;
constexpr float EPS = 1e-5f;

using short8 = __attribute__((ext_vector_type(8))) short;
using f32x4  = __attribute__((ext_vector_type(4))) float;

// ---------------- bf16 split helpers ----------------
__device__ __forceinline__ ushort bf16rne(float x) {
  unsigned u = __float_as_uint(x);
  unsigned r = (u + 0x7fffu + ((u >> 16) & 1u)) >> 16;
  return (ushort)r;
}
__device__ __forceinline__ void split2(float x, ushort& hi, ushort& lo) {
  hi = bf16rne(x);
  float hf = __uint_as_float((unsigned)hi << 16);
  lo = bf16rne(x - hf);
}

// ---------------- reductions ----------------
__device__ __forceinline__ void block_reduce2(float& s, float& ss) {
  #pragma unroll
  for (int o = 32; o > 0; o >>= 1) {
    s  += __shfl_down(s, o, 64);
    ss += __shfl_down(ss, o, 64);
  }
  __shared__ float ls[4], lss[4];
  const int lane = threadIdx.x & 63;
  const int w    = threadIdx.x >> 6;
  if (lane == 0) { ls[w] = s; lss[w] = ss; }
  __syncthreads();
  if (threadIdx.x == 0) {
    float a = 0.f, b2 = 0.f;
    #pragma unroll
    for (int i = 0; i < 4; ++i) { a += ls[i]; b2 += lss[i]; }
    ls[0] = a; lss[0] = b2;
  }
  __syncthreads();
  s = ls[0]; ss = lss[0];
}

// ---------------- LayerNorm -> bf16 hi/lo ----------------
__global__ __launch_bounds__(256) void ln_split_kernel(const float* __restrict__ x,
    const float* __restrict__ w, const float* __restrict__ b,
    ushort* __restrict__ oh, ushort* __restrict__ ol) {
  const int row = blockIdx.x;
  const int t   = threadIdx.x;
  const float4 v = reinterpret_cast<const float4*>(x + (size_t)row * HID)[t];
  float s  = v.x + v.y + v.z + v.w;
  float ss = v.x*v.x + v.y*v.y + v.z*v.z + v.w*v.w;
  block_reduce2(s, ss);
  const float mean = s * (1.f / HID);
  const float var  = ss * (1.f / HID) - mean * mean;
  const float rstd = rsqrtf(var + EPS);
  const float4 wv = reinterpret_cast<const float4*>(w)[t];
  const float4 bv = reinterpret_cast<const float4*>(b)[t];
  float o[4];
  o[0] = (v.x - mean) * rstd * wv.x + bv.x;
  o[1] = (v.y - mean) * rstd * wv.y + bv.y;
  o[2] = (v.z - mean) * rstd * wv.z + bv.z;
  o[3] = (v.w - mean) * rstd * wv.w + bv.w;
  ushort4 hv, lv;
  split2(o[0], hv.x, lv.x); split2(o[1], hv.y, lv.y);
  split2(o[2], hv.z, lv.z); split2(o[3], hv.w, lv.w);
  *reinterpret_cast<ushort4*>(oh + (size_t)row * HID + t * 4) = hv;
  *reinterpret_cast<ushort4*>(ol + (size_t)row * HID + t * 4) = lv;
}

// ---------------- weight transpose + split: W[K][N] -> T[N][K] hi/lo ----------------
__global__ __launch_bounds__(256) void wsplit_kernel(const float* __restrict__ W,
    ushort* __restrict__ Th, ushort* __restrict__ Tl, int N) {
  __shared__ float tile[32][33];
  const int k0 = blockIdx.y * 32;
  const int n0 = blockIdx.x * 32;
  const int tx = threadIdx.x & 31, ty = threadIdx.x >> 5;
  #pragma unroll
  for (int r = 0; r < 4; ++r)
    tile[ty + 8*r][tx] = W[(size_t)(k0 + ty + 8*r) * N + n0 + tx];
  __syncthreads();
  #pragma unroll
  for (int r = 0; r < 4; ++r) {
    const int n = ty + 8*r;
    const float v = tile[tx][n];
    ushort hi, lo; split2(v, hi, lo);
    Th[(size_t)(n0 + n) * 1024 + k0 + tx] = hi;
    Tl[(size_t)(n0 + n) * 1024 + k0 + tx] = lo;
  }
}

// ---------------- rotary tables: [s][m], m=0..15 ----------------
__global__ __launch_bounds__(256) void rot_tables_kernel(float* __restrict__ tcs,
    float* __restrict__ tsn, float* __restrict__ tscq, float* __restrict__ tsck) {
  const int g = blockIdx.x * 256 + threadIdx.x;   // 2048*16
  const int m = g & 15, s = g >> 4;
  const float invf = exp2f(-((float)(2 * m) * (1.f / 32.f)) * 13.287712379549449f);
  const float ang = (float)s * invf;
  tcs[g] = cosf(ang);
  tsn[g] = sinf(ang);
  const float p  = ((float)s - 1024.f) * (1.f / 512.f);
  const float sv = (2.f * (float)m + 12.8f) * (1.f / 44.8f);
  const float l  = log2f(sv) * p;
  tscq[g] = exp2f(l);
  tsck[g] = exp2f(-l);
}

// ---------------- epilogue helpers ----------------
__device__ __forceinline__ float mishf(float v) {
  return v * tanhf(log1pf(expf(v)));
}
__device__ __forceinline__ float geluf(float v) {
  return 0.5f * v * (1.f + erff(v * 0.7071067811865475f));
}

// ---------------- bf16x3 MFMA GEMM (EPI: 1 mish, 2 +res, 3 gelu(acc+bias)->split, 4 acc+bias+res) ----------------
template <int EPI>
__global__ __launch_bounds__(256, 2) void gemm_mfma(
    const ushort* __restrict__ Ah, const ushort* __restrict__ Al,
    const ushort* __restrict__ Bh, const ushort* __restrict__ Bl,
    const float* __restrict__ bias, const float* __restrict__ res,
    float* __restrict__ C, ushort* __restrict__ Ch, ushort* __restrict__ Cl,
    int N, int K) {
  __shared__ ushort sA[2][128 * 64];
  __shared__ ushort sB[2][128 * 64];
  const int tid  = threadIdx.x;
  const int lane = tid & 63;
  const int w    = tid >> 6;
  const int wm   = w >> 1, wn = w & 1;
  const int rowBase = blockIdx.y * 128;
  const int colBase = blockIdx.x * 128;

  f32x4 acc[4][4] = {};

  const int l8   = lane >> 3;
  const int kswz = ((lane & 7) * 16) ^ (l8 << 4);

  for (int k0 = 0; k0 < K; k0 += 64) {
    __syncthreads();
    #pragma unroll
    for (int c = 0; c < 4; ++c) {
      const int row = w * 32 + c * 8;
      const char* gah = (const char*)(Ah + (size_t)(rowBase + row + l8) * K + k0) + kswz;
      const char* gal = (const char*)(Al + (size_t)(rowBase + row + l8) * K + k0) + kswz;
      const char* gbh = (const char*)(Bh + (size_t)(colBase + row + l8) * K + k0) + kswz;
      const char* gbl = (const char*)(Bl + (size_t)(colBase + row + l8) * K + k0) + kswz;
      __builtin_amdgcn_global_load_lds((const __attribute__((address_space(1))) void*)gah,
          (__attribute__((address_space(3))) void*)((char*)sA[0] + row * 128), 16, 0, 0);
      __builtin_amdgcn_global_load_lds((const __attribute__((address_space(1))) void*)gal,
          (__attribute__((address_space(3))) void*)((char*)sA[1] + row * 128), 16, 0, 0);
      __builtin_amdgcn_global_load_lds((const __attribute__((address_space(1))) void*)gbh,
          (__attribute__((address_space(3))) void*)((char*)sB[0] + row * 128), 16, 0, 0);
      __builtin_amdgcn_global_load_lds((const __attribute__((address_space(1))) void*)gbl,
          (__attribute__((address_space(3))) void*)((char*)sB[1] + row * 128), 16, 0, 0);
    }
    __syncthreads();
    #pragma unroll
    for (int kk = 0; kk < 2; ++kk) {
      const int kb = kk * 64 + ((lane >> 4) << 4);
      short8 ah[4], al[4], bh[4], bl[4];
      #pragma unroll
      for (int i = 0; i < 4; ++i) {
        const int row = wm * 64 + i * 16 + (lane & 15);
        const int off = row * 128 + (kb ^ ((row & 7) << 4));
        ah[i] = *(const short8*)((const char*)sA[0] + off);
        al[i] = *(const short8*)((const char*)sA[1] + off);
      }
      #pragma unroll
      for (int j = 0; j < 4; ++j) {
        const int row = wn * 64 + j * 16 + (lane & 15);
        const int off = row * 128 + (kb ^ ((row & 7) << 4));
        bh[j] = *(const short8*)((const char*)sB[0] + off);
        bl[j] = *(const short8*)((const char*)sB[1] + off);
      }
      #pragma unroll
      for (int i = 0; i < 4; ++i)
        #pragma unroll
        for (int j = 0; j < 4; ++j) {
          acc[i][j] = __builtin_amdgcn_mfma_f32_16x16x32_bf16(ah[i], bh[j], acc[i][j], 0, 0, 0);
          acc[i][j] = __builtin_amdgcn_mfma_f32_16x16x32_bf16(ah[i], bl[j], acc[i][j], 0, 0, 0);
          acc[i][j] = __builtin_amdgcn_mfma_f32_16x16x32_bf16(al[i], bh[j], acc[i][j], 0, 0, 0);
        }
    }
  }

  const int cRow = rowBase + wm * 64 + ((lane >> 4) << 2);
  const int cCol = colBase + wn * 64 + (lane & 15);
  #pragma unroll
  for (int i = 0; i < 4; ++i)
    #pragma unroll
    for (int j = 0; j < 4; ++j) {
      const int gc = cCol + j * 16;
      #pragma unroll
      for (int r = 0; r < 4; ++r) {
        const int gr = cRow + i * 16 + r;
        float v = acc[i][j][r];
        if constexpr (EPI == 1) v = mishf(v);
        if constexpr (EPI == 2) v += res[(size_t)gr * N + gc];
        if constexpr (EPI == 3) v = geluf(v + bias[gc]);
        if constexpr (EPI == 4) v += bias[gc] + res[(size_t)gr * N + gc];
        if constexpr (EPI == 3) {
          ushort hi, lo; split2(v, hi, lo);
          Ch[(size_t)gr * N + gc] = hi;
          Cl[(size_t)gr * N + gc] = lo;
        } else {
          C[(size_t)gr * N + gc] = v;
        }
      }
    }
}

// ---------------- qkv GEMM with fused xPos rotary + layout emit ----------------
// q/k -> [b][h][s][d] bf16 hi/lo (rotary applied); v -> [b][h][d][s] bf16 hi/lo.
__global__ __launch_bounds__(256, 2) void gemm_qkv_rot(
    const ushort* __restrict__ Ah, const ushort* __restrict__ Al,
    const ushort* __restrict__ Bh, const ushort* __restrict__ Bl,
    const float* __restrict__ tcs, const float* __restrict__ tsn,
    const float* __restrict__ tscq, const float* __restrict__ tsck,
    ushort* __restrict__ qTh, ushort* __restrict__ qTl,
    ushort* __restrict__ kTh, ushort* __restrict__ kTl,
    ushort* __restrict__ vTh, ushort* __restrict__ vTl) {
  const int N = 3072, K = 1024;
  __shared__ ushort sA[2][128 * 64];
  __shared__ ushort sB[2][128 * 64];
  const int tid  = threadIdx.x;
  const int lane = tid & 63;
  const int w    = tid >> 6;
  const int wm   = w >> 1, wn = w & 1;
  const int rowBase = blockIdx.y * 128;
  const int colBase = blockIdx.x * 128;

  f32x4 acc[4][4] = {};

  const int l8   = lane >> 3;
  const int kswz = ((lane & 7) * 16) ^ (l8 << 4);

  for (int k0 = 0; k0 < K; k0 += 64) {
    __syncthreads();
    #pragma unroll
    for (int c = 0; c < 4; ++c) {
      const int row = w * 32 + c * 8;
      const char* gah = (const char*)(Ah + (size_t)(rowBase + row + l8) * K + k0) + kswz;
      const char* gal = (const char*)(Al + (size_t)(rowBase + row + l8) * K + k0) + kswz;
      const char* gbh = (const char*)(Bh + (size_t)(colBase + row + l8) * K + k0) + kswz;
      const char* gbl = (const char*)(Bl + (size_t)(colBase + row + l8) * K + k0) + kswz;
      __builtin_amdgcn_global_load_lds((const __attribute__((address_space(1))) void*)gah,
          (__attribute__((address_space(3))) void*)((char*)sA[0] + row * 128), 16, 0, 0);
      __builtin_amdgcn_global_load_lds((const __attribute__((address_space(1))) void*)gal,
          (__attribute__((address_space(3))) void*)((char*)sA[1] + row * 128), 16, 0, 0);
      __builtin_amdgcn_global_load_lds((const __attribute__((address_space(1))) void*)gbh,
          (__attribute__((address_space(3))) void*)((char*)sB[0] + row * 128), 16, 0, 0);
      __builtin_amdgcn_global_load_lds((const __attribute__((address_space(1))) void*)gbl,
          (__attribute__((address_space(3))) void*)((char*)sB[1] + row * 128), 16, 0, 0);
    }
    __syncthreads();
    #pragma unroll
    for (int kk = 0; kk < 2; ++kk) {
      const int kb = kk * 64 + ((lane >> 4) << 4);
      short8 ah[4], al[4], bh[4], bl[4];
      #pragma unroll
      for (int i = 0; i < 4; ++i) {
        const int row = wm * 64 + i * 16 + (lane & 15);
        const int off = row * 128 + (kb ^ ((row & 7) << 4));
        ah[i] = *(const short8*)((const char*)sA[0] + off);
        al[i] = *(const short8*)((const char*)sA[1] + off);
      }
      #pragma unroll
      for (int j = 0; j < 4; ++j) {
        const int row = wn * 64 + j * 16 + (lane & 15);
        const int off = row * 128 + (kb ^ ((row & 7) << 4));
        bh[j] = *(const short8*)((const char*)sB[0] + off);
        bl[j] = *(const short8*)((const char*)sB[1] + off);
      }
      #pragma unroll
      for (int i = 0; i < 4; ++i)
        #pragma unroll
        for (int j = 0; j < 4; ++j) {
          acc[i][j] = __builtin_amdgcn_mfma_f32_16x16x32_bf16(ah[i], bh[j], acc[i][j], 0, 0, 0);
          acc[i][j] = __builtin_amdgcn_mfma_f32_16x16x32_bf16(ah[i], bl[j], acc[i][j], 0, 0, 0);
          acc[i][j] = __builtin_amdgcn_mfma_f32_16x16x32_bf16(al[i], bh[j], acc[i][j], 0, 0, 0);
        }
    }
  }

  // epilogue: each wave's 64-col strip is entirely q, k, or v (c0 % 192 in {0,64,128})
  const int c0     = colBase + wn * 64;
  const int region = (c0 >> 6) % 3;       // 0=q, 1=k, 2=v
  const int hh     = c0 / 192;
  const int cRow   = rowBase + wm * 64 + ((lane >> 4) << 2);
  const int lc     = lane & 15;

  if (region == 2) {
    #pragma unroll
    for (int j = 0; j < 4; ++j) {
      const int d = 16 * j + lc;
      #pragma unroll
      for (int i = 0; i < 4; ++i) {
        const int s0g = cRow + i * 16;
        const int bb  = s0g >> 11;
        const int s0  = s0g & 2047;
        ushort4 hv, lv;
        #pragma unroll
        for (int r = 0; r < 4; ++r) {
          ushort hi, lo; split2(acc[i][j][r], hi, lo);
          ((ushort*)&hv)[r] = hi; ((ushort*)&lv)[r] = lo;
        }
        const size_t a = ((size_t)(bb * NH + hh) * HD + d) * S_LEN + s0;
        *reinterpret_cast<ushort4*>(vTh + a) = hv;
        *reinterpret_cast<ushort4*>(vTl + a) = lv;
      }
    }
  } else {
    ushort* Oh = (region == 0) ? qTh : kTh;
    ushort* Ol = (region == 0) ? qTl : kTl;
    const float* tsc = (region == 0) ? tscq : tsck;
    #pragma unroll
    for (int j = 0; j < 4; ++j) {
      const int d  = 16 * j + lc;
      const int ii = d >> 1;
      const int im = d & 15;
      #pragma unroll
      for (int i = 0; i < 4; ++i) {
        const int s0g = cRow + i * 16;
        const int bb  = s0g >> 11;
        #pragma unroll
        for (int r = 0; r < 4; ++r) {
          const int s = (s0g + r) & 2047;
          float v = acc[i][j][r];
          float p = __shfl_xor(v, 1);
          float resv;
          if (j < 2) {  // d < 32: rotated + scaled
            const float cs  = tcs[s * 16 + ii];
            const float sn  = tsn[s * 16 + ii];
            const float scl = tsc[s * 16 + im];
            resv = ((lane & 1) ? (v * cs + p * sn) : (v * cs - p * sn)) * scl;
          } else {
            resv = v;
          }
          ushort hi, lo; split2(resv, hi, lo);
          const size_t a = ((size_t)(bb * NH + hh) * S_LEN + s) * HD + d;
          Oh[a] = hi; Ol[a] = lo;
        }
      }
    }
  }
}

// ---------------- MFMA retention: ret = (QK^T * gamma^(s-t) [s>=t]) V ----------------
__global__ __launch_bounds__(256, 2) void retention_mfma(
    const ushort* __restrict__ qTh, const ushort* __restrict__ qTl,
    const ushort* __restrict__ kTh, const ushort* __restrict__ kTl,
    const ushort* __restrict__ vTh, const ushort* __restrict__ vTl,
    float* __restrict__ ret) {
  const int sblk = blockIdx.x, h = blockIdx.y, b = blockIdx.z;
  const int tid = threadIdx.x, lane = tid & 63, w = tid >> 6;
  const int sBase = sblk << 6;
  const float l2g = log2f(1.f - exp2f(-5.f - (float)h));   // negative

  __shared__ ushort Qh[4096], Ql[4096], Kh[4096], Kl[4096],
                    Vh[4096], Vl[4096], Sh[4096], Sl[4096];

  const int l8   = lane >> 3;
  const int kswz = ((lane & 7) * 16) ^ (l8 << 4);

  auto stage16 = [&](const ushort* src, int pitch, ushort* dst, int r0) {
    #pragma unroll
    for (int c = 0; c < 2; ++c) {
      const int row = r0 + c * 8;
      const char* g = (const char*)(src + (size_t)(row + l8) * pitch) + kswz;
      __builtin_amdgcn_global_load_lds((const __attribute__((address_space(1))) void*)g,
          (__attribute__((address_space(3))) void*)((char*)dst + row * 128), 16, 0, 0);
    }
  };

  const size_t bh  = (size_t)(b * NH + h);
  const size_t bho = bh * (S_LEN * HD);

  stage16(qTh + bho + (size_t)sBase * HD, 64, Qh, w * 16);
  stage16(qTl + bho + (size_t)sBase * HD, 64, Ql, w * 16);

  // decay per-lane constants (hoisted out of t-loop)
  const int sQr = (lane >> 4) << 2;
  float gs[4], gti[4];
  #pragma unroll
  for (int r = 0; r < 4; ++r) gs[r] = exp2f(l2g * (float)(w * 16 + sQr + r));
  #pragma unroll
  for (int j = 0; j < 4; ++j) gti[j] = exp2f(-l2g * (float)((lane & 15) + 16 * j));

  f32x4 acc[4] = {};

  const int aRow = w * 16 + (lane & 15);
  const int aOff = aRow * 128;
  const int aswz = (aRow & 7) << 4;

  for (int tblk = 0; tblk <= sblk; ++tblk) {
    const int tBase = tblk << 6;
    const int nmin  = sBase - tBase - 63;
    if (nmin > 0 && (float)nmin * l2g < -45.f) continue;   // gamma^n negligible
    __syncthreads();   // previous S/V consumed
    stage16(kTh + bho + (size_t)tBase * HD, 64,   Kh, w * 16);
    stage16(kTl + bho + (size_t)tBase * HD, 64,   Kl, w * 16);
    stage16(vTh + bho + tBase,              2048, Vh, w * 16);
    stage16(vTl + bho + tBase,              2048, Vl, w * 16);
    __syncthreads();   // drain staging

    // QK^T (bf16x3)
    f32x4 sc[4] = {};
    #pragma unroll
    for (int ks = 0; ks < 2; ++ks) {
      const int kb = ks * 64 + ((lane >> 4) << 4);
      const short8 qhf = *(const short8*)((const char*)Qh + aOff + (kb ^ aswz));
      const short8 qlf = *(const short8*)((const char*)Ql + aOff + (kb ^ aswz));
      #pragma unroll
      for (int j = 0; j < 4; ++j) {
        const int br = j * 16 + (lane & 15);
        const int bo = br * 128 + (kb ^ ((br & 7) << 4));
        const short8 khf = *(const short8*)((const char*)Kh + bo);
        const short8 klf = *(const short8*)((const char*)Kl + bo);
        sc[j] = __builtin_amdgcn_mfma_f32_16x16x32_bf16(qhf, khf, sc[j], 0, 0, 0);
        sc[j] = __builtin_amdgcn_mfma_f32_16x16x32_bf16(qhf, klf, sc[j], 0, 0, 0);
        sc[j] = __builtin_amdgcn_mfma_f32_16x16x32_bf16(qlf, khf, sc[j], 0, 0, 0);
      }
    }

    // decay + split + write S^ to LDS
    const float D0  = exp2f(l2g * (float)(sBase - tBase));
    const bool diag = (tBase == sBase);
    #pragma unroll
    for (int j = 0; j < 4; ++j) {
      const int tLoc  = (lane & 15) + 16 * j;
      const float gj  = D0 * gti[j];
      #pragma unroll
      for (int r = 0; r < 4; ++r) {
        const int sLoc = w * 16 + sQr + r;
        float dec = gj * gs[r];
        if (diag && sLoc < tLoc) dec = 0.f;
        const float v = sc[j][r] * dec;
        ushort hi, lo; split2(v, hi, lo);
        const int off = sLoc * 128 + ((tLoc * 2) ^ ((sLoc & 7) << 4));
        *(ushort*)((char*)Sh + off) = hi;
        *(ushort*)((char*)Sl + off) = lo;
      }
    }
    __syncthreads();   // S^ visible

    // PV (bf16x3) accumulate
    #pragma unroll
    for (int ks = 0; ks < 2; ++ks) {
      const int kb = ks * 64 + ((lane >> 4) << 4);
      const short8 shf = *(const short8*)((const char*)Sh + aOff + (kb ^ aswz));
      const short8 slf = *(const short8*)((const char*)Sl + aOff + (kb ^ aswz));
      #pragma unroll
      for (int j = 0; j < 4; ++j) {
        const int br = j * 16 + (lane & 15);
        const int bo = br * 128 + (kb ^ ((br & 7) << 4));
        const short8 vhf = *(const short8*)((const char*)Vh + bo);
        const short8 vlf = *(const short8*)((const char*)Vl + bo);
        acc[j] = __builtin_amdgcn_mfma_f32_16x16x32_bf16(shf, vhf, acc[j], 0, 0, 0);
        acc[j] = __builtin_amdgcn_mfma_f32_16x16x32_bf16(shf, vlf, acc[j], 0, 0, 0);
        acc[j] = __builtin_amdgcn_mfma_f32_16x16x32_bf16(slf, vhf, acc[j], 0, 0, 0);
      }
    }
  }

  float* ob = ret + (bh * S_LEN + sBase) * HD;
  #pragma unroll
  for (int j = 0; j < 4; ++j)
    #pragma unroll
    for (int r = 0; r < 4; ++r)
      ob[(w * 16 + sQr + r) * 64 + j * 16 + (lane & 15)] = acc[j][r];
}

// ---------------- group norm + gate, emitting bf16 hi/lo ----------------
__global__ __launch_bounds__(256) void gn_kernel(const float* __restrict__ ret,
    const float* __restrict__ gm, const float* __restrict__ gn_w, const float* __restrict__ gn_b,
    ushort* __restrict__ yh, ushort* __restrict__ yl) {
  const int bh = blockIdx.x;
  const int b = bh >> 4, h = bh & 15;
  const float4* r4 = reinterpret_cast<const float4*>(ret + (size_t)bh * (S_LEN * HD));
  float s = 0.f, ss = 0.f;
  for (int i = threadIdx.x; i < S_LEN * HD / 4; i += 256) {
    const float4 v = r4[i];
    s  += v.x + v.y + v.z + v.w;
    ss += v.x*v.x + v.y*v.y + v.z*v.z + v.w*v.w;
  }
  block_reduce2(s, ss);
  const float inv  = 1.f / (float)(S_LEN * HD);
  const float mean = s * inv;
  const float var  = ss * inv - mean * mean;
  const float rstd = rsqrtf(var + EPS);
  const float a = gn_w[h] * rstd;
  const float c = gn_b[h] - mean * a;
  for (int i = threadIdx.x; i < S_LEN * HD / 4; i += 256) {
    const float4 v = r4[i];
    const int e    = i << 2;
    const int srow = e >> 6;
    const int d    = e & 63;
    const size_t oidx = (size_t)(b * S_LEN + srow) * HID + h * HD + d;
    const float4 g = *reinterpret_cast<const float4*>(gm + oidx);
    float o0 = (v.x * a + c) * g.x;
    float o1 = (v.y * a + c) * g.y;
    float o2 = (v.z * a + c) * g.z;
    float o3 = (v.w * a + c) * g.w;
    ushort4 hv, lv;
    split2(o0, hv.x, lv.x); split2(o1, hv.y, lv.y);
    split2(o2, hv.z, lv.z); split2(o3, hv.w, lv.w);
    *reinterpret_cast<ushort4*>(yh + oidx) = hv;
    *reinterpret_cast<ushort4*>(yl + oidx) = lv;
  }
}

// ---------------- launcher ----------------
extern "C" void kernel_launch(void* const* d_in, const int* in_sizes, int n_in,
                              void* d_out, int out_size, void* d_ws, size_t ws_size,
                              hipStream_t stream) {
  const float* x     = (const float*)d_in[0];
  const float* ln1_w = (const float*)d_in[1];
  const float* ln1_b = (const float*)d_in[2];
  const float* wqkv  = (const float*)d_in[3];
  const float* wg    = (const float*)d_in[4];
  const float* wo    = (const float*)d_in[5];
  const float* gn_w  = (const float*)d_in[6];
  const float* gn_b  = (const float*)d_in[7];
  const float* ln2_w = (const float*)d_in[8];
  const float* ln2_b = (const float*)d_in[9];
  const float* w1    = (const float*)d_in[10];
  const float* w1_b  = (const float*)d_in[11];
  const float* w2    = (const float*)d_in[12];
  const float* w2_b  = (const float*)d_in[13];

  char* ws = (char*)d_ws;
  ushort* wqkvT_h = (ushort*)(ws + 0);
  ushort* wqkvT_l = (ushort*)(ws + 6291456);
  ushort* wgT_h   = (ushort*)(ws + 12582912);
  ushort* wgT_l   = (ushort*)(ws + 14680064);
  ushort* woT_h   = (ushort*)(ws + 16777216);
  ushort* woT_l   = (ushort*)(ws + 18874368);
  ushort* w1T_h   = (ushort*)(ws + 20971520);
  ushort* w1T_l   = (ushort*)(ws + 23068672);
  ushort* w2T_h   = (ushort*)(ws + 25165824);
  ushort* w2T_l   = (ushort*)(ws + 27262976);
  ushort* h_hi    = (ushort*)(ws + 29360128);
  ushort* h_lo    = (ushort*)(ws + 37748736);
  float*  tcs     = (float*) (ws + 46137344);
  float*  tsn     = (float*) (ws + 46268416);
  float*  tscq    = (float*) (ws + 46399488);
  float*  tsck    = (float*) (ws + 46530560);
  ushort* qT_h    = (ushort*)(ws + 46661632);
  ushort* qT_l    = (ushort*)(ws + 55050240);
  ushort* kT_h    = (ushort*)(ws + 63438848);
  ushort* kT_l    = (ushort*)(ws + 71827456);
  ushort* vT_h    = (ushort*)(ws + 80216064);
  ushort* vT_l    = (ushort*)(ws + 88604672);
  float*  gmish   = (float*) (ws + 96993280);
  // reuses (stream-ordered):
  float*  ret     = (float*) (ws + 29360128);   // h region (dead after gemm_qkv_rot)
  ushort* yin_h   = (ushort*)(ws + 46661632);   // qT region (dead after retention)
  ushort* yin_l   = (ushort*)(ws + 55050240);
  float*  y       = (float*) (ws + 63438848);   // kT region
  ushort* z_h     = (ushort*)(ws + 80216064);   // vT region
  ushort* z_l     = (ushort*)(ws + 88604672);
  ushort* f_h     = (ushort*)(ws + 96993280);   // gmish region (dead after gn)
  ushort* f_l     = (ushort*)(ws + 105381888);  // ends 113,770,496
  float*  out     = (float*)d_out;

  wsplit_kernel<<<dim3(3072/32, 32), 256, 0, stream>>>(wqkv, wqkvT_h, wqkvT_l, 3072);
  wsplit_kernel<<<dim3(1024/32, 32), 256, 0, stream>>>(wg, wgT_h, wgT_l, 1024);
  wsplit_kernel<<<dim3(1024/32, 32), 256, 0, stream>>>(wo, woT_h, woT_l, 1024);
  wsplit_kernel<<<dim3(1024/32, 32), 256, 0, stream>>>(w1, w1T_h, w1T_l, 1024);
  wsplit_kernel<<<dim3(1024/32, 32), 256, 0, stream>>>(w2, w2T_h, w2T_l, 1024);
  rot_tables_kernel<<<128, 256, 0, stream>>>(tcs, tsn, tscq, tsck);

  ln_split_kernel<<<BATCH * S_LEN, 256, 0, stream>>>(x, ln1_w, ln1_b, h_hi, h_lo);
  gemm_mfma<1><<<dim3(1024/128, 4096/128), 256, 0, stream>>>(h_hi, h_lo, wgT_h, wgT_l,
      nullptr, nullptr, gmish, nullptr, nullptr, 1024, 1024);
  gemm_qkv_rot<<<dim3(3072/128, 4096/128), 256, 0, stream>>>(h_hi, h_lo, wqkvT_h, wqkvT_l,
      tcs, tsn, tscq, tsck, qT_h, qT_l, kT_h, kT_l, vT_h, vT_l);
  retention_mfma<<<dim3(S_LEN/64, NH, BATCH), 256, 0, stream>>>(qT_h, qT_l, kT_h, kT_l,
      vT_h, vT_l, ret);
  gn_kernel<<<BATCH * NH, 256, 0, stream>>>(ret, gmish, gn_w, gn_b, yin_h, yin_l);
  gemm_mfma<2><<<dim3(1024/128, 4096/128), 256, 0, stream>>>(yin_h, yin_l, woT_h, woT_l,
      nullptr, x, y, nullptr, nullptr, 1024, 1024);
  ln_split_kernel<<<BATCH * S_LEN, 256, 0, stream>>>(y, ln2_w, ln2_b, z_h, z_l);
  gemm_mfma<3><<<dim3(1024/128, 4096/128), 256, 0, stream>>>(z_h, z_l, w1T_h, w1T_l,
      w1_b, nullptr, nullptr, f_h, f_l, 1024, 1024);
  gemm_mfma<4><<<dim3(1024/128, 4096/128), 256, 0, stream>>>(f_h, f_l, w2T_h, w2T_l,
      w2_b, y, out, nullptr, nullptr, 1024, 1024);
}

// Round 7
// 581.969 us; speedup vs baseline: 3.5310x; 1.0560x over previous
//
#include <hip/hip_runtime.h>

// RetNet block: bf16x3 MFMA GEMMs (merged qkv+gate, BN=64 tiles for N=1024) + MFMA retention.
// Workspace usage: 113,770,496 bytes.

constexpr int S_LEN = 2048;
constexpr int HID   = 1024;
constexpr int NH    = 16;
constexpr int HD    = 64;
constexpr int BATCH = 2;
constexpr float EPS = 1e-5f;

using short8 = __attribute__((ext_vector_type(8))) short;
using f32x4  = __attribute__((ext_vector_type(4))) float;

// ---------------- bf16 split helpers ----------------
__device__ __forceinline__ ushort bf16rne(float x) {
  unsigned u = __float_as_uint(x);
  unsigned r = (u + 0x7fffu + ((u >> 16) & 1u)) >> 16;
  return (ushort)r;
}
__device__ __forceinline__ void split2(float x, ushort& hi, ushort& lo) {
  hi = bf16rne(x);
  float hf = __uint_as_float((unsigned)hi << 16);
  lo = bf16rne(x - hf);
}

// ---------------- reductions ----------------
__device__ __forceinline__ void block_reduce2(float& s, float& ss) {
  #pragma unroll
  for (int o = 32; o > 0; o >>= 1) {
    s  += __shfl_down(s, o, 64);
    ss += __shfl_down(ss, o, 64);
  }
  __shared__ float ls[4], lss[4];
  const int lane = threadIdx.x & 63;
  const int w    = threadIdx.x >> 6;
  if (lane == 0) { ls[w] = s; lss[w] = ss; }
  __syncthreads();
  if (threadIdx.x == 0) {
    float a = 0.f, b2 = 0.f;
    #pragma unroll
    for (int i = 0; i < 4; ++i) { a += ls[i]; b2 += lss[i]; }
    ls[0] = a; lss[0] = b2;
  }
  __syncthreads();
  s = ls[0]; ss = lss[0];
}

// ---------------- LayerNorm -> bf16 hi/lo ----------------
__global__ __launch_bounds__(256) void ln_split_kernel(const float* __restrict__ x,
    const float* __restrict__ w, const float* __restrict__ b,
    ushort* __restrict__ oh, ushort* __restrict__ ol) {
  const int row = blockIdx.x;
  const int t   = threadIdx.x;
  const float4 v = reinterpret_cast<const float4*>(x + (size_t)row * HID)[t];
  float s  = v.x + v.y + v.z + v.w;
  float ss = v.x*v.x + v.y*v.y + v.z*v.z + v.w*v.w;
  block_reduce2(s, ss);
  const float mean = s * (1.f / HID);
  const float var  = ss * (1.f / HID) - mean * mean;
  const float rstd = rsqrtf(var + EPS);
  const float4 wv = reinterpret_cast<const float4*>(w)[t];
  const float4 bv = reinterpret_cast<const float4*>(b)[t];
  float o[4];
  o[0] = (v.x - mean) * rstd * wv.x + bv.x;
  o[1] = (v.y - mean) * rstd * wv.y + bv.y;
  o[2] = (v.z - mean) * rstd * wv.z + bv.z;
  o[3] = (v.w - mean) * rstd * wv.w + bv.w;
  ushort4 hv, lv;
  split2(o[0], hv.x, lv.x); split2(o[1], hv.y, lv.y);
  split2(o[2], hv.z, lv.z); split2(o[3], hv.w, lv.w);
  *reinterpret_cast<ushort4*>(oh + (size_t)row * HID + t * 4) = hv;
  *reinterpret_cast<ushort4*>(ol + (size_t)row * HID + t * 4) = lv;
}

// ---------------- weight transpose + split: W[K][N] -> T[N][K] hi/lo ----------------
__global__ __launch_bounds__(256) void wsplit_kernel(const float* __restrict__ W,
    ushort* __restrict__ Th, ushort* __restrict__ Tl, int N) {
  __shared__ float tile[32][33];
  const int k0 = blockIdx.y * 32;
  const int n0 = blockIdx.x * 32;
  const int tx = threadIdx.x & 31, ty = threadIdx.x >> 5;
  #pragma unroll
  for (int r = 0; r < 4; ++r)
    tile[ty + 8*r][tx] = W[(size_t)(k0 + ty + 8*r) * N + n0 + tx];
  __syncthreads();
  #pragma unroll
  for (int r = 0; r < 4; ++r) {
    const int n = ty + 8*r;
    const float v = tile[tx][n];
    ushort hi, lo; split2(v, hi, lo);
    Th[(size_t)(n0 + n) * 1024 + k0 + tx] = hi;
    Tl[(size_t)(n0 + n) * 1024 + k0 + tx] = lo;
  }
}

// ---------------- rotary tables: [s][m], m=0..15 ----------------
__global__ __launch_bounds__(256) void rot_tables_kernel(float* __restrict__ tcs,
    float* __restrict__ tsn, float* __restrict__ tscq, float* __restrict__ tsck) {
  const int g = blockIdx.x * 256 + threadIdx.x;
  const int m = g & 15, s = g >> 4;
  const float invf = exp2f(-((float)(2 * m) * (1.f / 32.f)) * 13.287712379549449f);
  const float ang = (float)s * invf;
  tcs[g] = cosf(ang);
  tsn[g] = sinf(ang);
  const float p  = ((float)s - 1024.f) * (1.f / 512.f);
  const float sv = (2.f * (float)m + 12.8f) * (1.f / 44.8f);
  const float l  = log2f(sv) * p;
  tscq[g] = exp2f(l);
  tsck[g] = exp2f(-l);
}

// ---------------- epilogue helpers ----------------
__device__ __forceinline__ float mishf(float v) {
  return v * tanhf(log1pf(expf(v)));
}
__device__ __forceinline__ float geluf(float v) {
  return 0.5f * v * (1.f + erff(v * 0.7071067811865475f));
}

// ---------------- bf16x3 MFMA GEMM, tile 128 x BN ----------------
// EPI: 2 +res, 3 gelu(acc+bias)->split out, 4 acc+bias+res
template <int EPI, int BN>
__global__ __launch_bounds__(256, 2) void gemm_mfma(
    const ushort* __restrict__ Ah, const ushort* __restrict__ Al,
    const ushort* __restrict__ Bh, const ushort* __restrict__ Bl,
    const float* __restrict__ bias, const float* __restrict__ res,
    float* __restrict__ C, ushort* __restrict__ Ch, ushort* __restrict__ Cl,
    int N, int K) {
  constexpr int MI  = (BN == 128) ? 4 : 2;     // 16-row fragments per wave
  constexpr int BCH = BN / 32;                 // B staging chunks per wave
  __shared__ ushort sA[2][128 * 64];
  __shared__ ushort sB[2][BN * 64];
  const int tid  = threadIdx.x;
  const int lane = tid & 63;
  const int w    = tid >> 6;
  const int wm   = (BN == 128) ? (w >> 1) : w;
  const int wn   = (BN == 128) ? (w & 1)  : 0;
  const int rowBase = blockIdx.y * 128;
  const int colBase = blockIdx.x * BN;

  f32x4 acc[MI][4] = {};

  const int l8   = lane >> 3;
  const int kswz = ((lane & 7) * 16) ^ (l8 << 4);

  for (int k0 = 0; k0 < K; k0 += 64) {
    __syncthreads();
    #pragma unroll
    for (int c = 0; c < 4; ++c) {
      const int row = w * 32 + c * 8;
      const char* gah = (const char*)(Ah + (size_t)(rowBase + row + l8) * K + k0) + kswz;
      const char* gal = (const char*)(Al + (size_t)(rowBase + row + l8) * K + k0) + kswz;
      __builtin_amdgcn_global_load_lds((const __attribute__((address_space(1))) void*)gah,
          (__attribute__((address_space(3))) void*)((char*)sA[0] + row * 128), 16, 0, 0);
      __builtin_amdgcn_global_load_lds((const __attribute__((address_space(1))) void*)gal,
          (__attribute__((address_space(3))) void*)((char*)sA[1] + row * 128), 16, 0, 0);
    }
    #pragma unroll
    for (int c = 0; c < BCH; ++c) {
      const int row = w * (BN / 4) + c * 8;
      const char* gbh = (const char*)(Bh + (size_t)(colBase + row + l8) * K + k0) + kswz;
      const char* gbl = (const char*)(Bl + (size_t)(colBase + row + l8) * K + k0) + kswz;
      __builtin_amdgcn_global_load_lds((const __attribute__((address_space(1))) void*)gbh,
          (__attribute__((address_space(3))) void*)((char*)sB[0] + row * 128), 16, 0, 0);
      __builtin_amdgcn_global_load_lds((const __attribute__((address_space(1))) void*)gbl,
          (__attribute__((address_space(3))) void*)((char*)sB[1] + row * 128), 16, 0, 0);
    }
    __syncthreads();
    #pragma unroll
    for (int kk = 0; kk < 2; ++kk) {
      const int kb = kk * 64 + ((lane >> 4) << 4);
      short8 ah[MI], al[MI], bh[4], bl[4];
      #pragma unroll
      for (int i = 0; i < MI; ++i) {
        const int row = wm * (16 * MI) + i * 16 + (lane & 15);
        const int off = row * 128 + (kb ^ ((row & 7) << 4));
        ah[i] = *(const short8*)((const char*)sA[0] + off);
        al[i] = *(const short8*)((const char*)sA[1] + off);
      }
      #pragma unroll
      for (int j = 0; j < 4; ++j) {
        const int row = wn * 64 + j * 16 + (lane & 15);
        const int off = row * 128 + (kb ^ ((row & 7) << 4));
        bh[j] = *(const short8*)((const char*)sB[0] + off);
        bl[j] = *(const short8*)((const char*)sB[1] + off);
      }
      #pragma unroll
      for (int i = 0; i < MI; ++i)
        #pragma unroll
        for (int j = 0; j < 4; ++j) {
          acc[i][j] = __builtin_amdgcn_mfma_f32_16x16x32_bf16(ah[i], bh[j], acc[i][j], 0, 0, 0);
          acc[i][j] = __builtin_amdgcn_mfma_f32_16x16x32_bf16(ah[i], bl[j], acc[i][j], 0, 0, 0);
          acc[i][j] = __builtin_amdgcn_mfma_f32_16x16x32_bf16(al[i], bh[j], acc[i][j], 0, 0, 0);
        }
    }
  }

  const int cRow = rowBase + wm * (16 * MI) + ((lane >> 4) << 2);
  const int cCol = colBase + wn * 64 + (lane & 15);
  #pragma unroll
  for (int i = 0; i < MI; ++i)
    #pragma unroll
    for (int j = 0; j < 4; ++j) {
      const int gc = cCol + j * 16;
      #pragma unroll
      for (int r = 0; r < 4; ++r) {
        const int gr = cRow + i * 16 + r;
        float v = acc[i][j][r];
        if constexpr (EPI == 2) v += res[(size_t)gr * N + gc];
        if constexpr (EPI == 3) v = geluf(v + bias[gc]);
        if constexpr (EPI == 4) v += bias[gc] + res[(size_t)gr * N + gc];
        if constexpr (EPI == 3) {
          ushort hi, lo; split2(v, hi, lo);
          Ch[(size_t)gr * N + gc] = hi;
          Cl[(size_t)gr * N + gc] = lo;
        } else {
          C[(size_t)gr * N + gc] = v;
        }
      }
    }
}

// ---------------- merged qkv+gate GEMM with fused xPos rotary + layout emit ----------------
// B^T = [wqkv^T ; wg^T] (4096 x 1024). Cols 0..3071: q/k/v per head; cols 3072..4095: mish gate.
__global__ __launch_bounds__(256, 2) void gemm_qkvg_rot(
    const ushort* __restrict__ Ah, const ushort* __restrict__ Al,
    const ushort* __restrict__ Bh, const ushort* __restrict__ Bl,
    const float* __restrict__ tcs, const float* __restrict__ tsn,
    const float* __restrict__ tscq, const float* __restrict__ tsck,
    ushort* __restrict__ qTh, ushort* __restrict__ qTl,
    ushort* __restrict__ kTh, ushort* __restrict__ kTl,
    ushort* __restrict__ vTh, ushort* __restrict__ vTl,
    float* __restrict__ gmish) {
  const int K = 1024;
  __shared__ ushort sA[2][128 * 64];
  __shared__ ushort sB[2][128 * 64];
  const int tid  = threadIdx.x;
  const int lane = tid & 63;
  const int w    = tid >> 6;
  const int wm   = w >> 1, wn = w & 1;
  const int rowBase = blockIdx.y * 128;
  const int colBase = blockIdx.x * 128;

  f32x4 acc[4][4] = {};

  const int l8   = lane >> 3;
  const int kswz = ((lane & 7) * 16) ^ (l8 << 4);

  for (int k0 = 0; k0 < K; k0 += 64) {
    __syncthreads();
    #pragma unroll
    for (int c = 0; c < 4; ++c) {
      const int row = w * 32 + c * 8;
      const char* gah = (const char*)(Ah + (size_t)(rowBase + row + l8) * K + k0) + kswz;
      const char* gal = (const char*)(Al + (size_t)(rowBase + row + l8) * K + k0) + kswz;
      const char* gbh = (const char*)(Bh + (size_t)(colBase + row + l8) * K + k0) + kswz;
      const char* gbl = (const char*)(Bl + (size_t)(colBase + row + l8) * K + k0) + kswz;
      __builtin_amdgcn_global_load_lds((const __attribute__((address_space(1))) void*)gah,
          (__attribute__((address_space(3))) void*)((char*)sA[0] + row * 128), 16, 0, 0);
      __builtin_amdgcn_global_load_lds((const __attribute__((address_space(1))) void*)gal,
          (__attribute__((address_space(3))) void*)((char*)sA[1] + row * 128), 16, 0, 0);
      __builtin_amdgcn_global_load_lds((const __attribute__((address_space(1))) void*)gbh,
          (__attribute__((address_space(3))) void*)((char*)sB[0] + row * 128), 16, 0, 0);
      __builtin_amdgcn_global_load_lds((const __attribute__((address_space(1))) void*)gbl,
          (__attribute__((address_space(3))) void*)((char*)sB[1] + row * 128), 16, 0, 0);
    }
    __syncthreads();
    #pragma unroll
    for (int kk = 0; kk < 2; ++kk) {
      const int kb = kk * 64 + ((lane >> 4) << 4);
      short8 ah[4], al[4], bh[4], bl[4];
      #pragma unroll
      for (int i = 0; i < 4; ++i) {
        const int row = wm * 64 + i * 16 + (lane & 15);
        const int off = row * 128 + (kb ^ ((row & 7) << 4));
        ah[i] = *(const short8*)((const char*)sA[0] + off);
        al[i] = *(const short8*)((const char*)sA[1] + off);
      }
      #pragma unroll
      for (int j = 0; j < 4; ++j) {
        const int row = wn * 64 + j * 16 + (lane & 15);
        const int off = row * 128 + (kb ^ ((row & 7) << 4));
        bh[j] = *(const short8*)((const char*)sB[0] + off);
        bl[j] = *(const short8*)((const char*)sB[1] + off);
      }
      #pragma unroll
      for (int i = 0; i < 4; ++i)
        #pragma unroll
        for (int j = 0; j < 4; ++j) {
          acc[i][j] = __builtin_amdgcn_mfma_f32_16x16x32_bf16(ah[i], bh[j], acc[i][j], 0, 0, 0);
          acc[i][j] = __builtin_amdgcn_mfma_f32_16x16x32_bf16(ah[i], bl[j], acc[i][j], 0, 0, 0);
          acc[i][j] = __builtin_amdgcn_mfma_f32_16x16x32_bf16(al[i], bh[j], acc[i][j], 0, 0, 0);
        }
    }
  }

  // epilogue: each wave's 64-col strip is entirely q, k, v, or gate
  const int c0   = colBase + wn * 64;
  const int cRow = rowBase + wm * 64 + ((lane >> 4) << 2);
  const int lc   = lane & 15;

  if (c0 >= 3072) {              // gate region: mish -> gmish fp32 [4096][1024]
    const int gc0 = c0 - 3072;
    #pragma unroll
    for (int i = 0; i < 4; ++i)
      #pragma unroll
      for (int j = 0; j < 4; ++j) {
        const int gc = gc0 + j * 16 + lc;
        #pragma unroll
        for (int r = 0; r < 4; ++r) {
          const int gr = cRow + i * 16 + r;
          gmish[(size_t)gr * 1024 + gc] = mishf(acc[i][j][r]);
        }
      }
    return;
  }
  const int region = (c0 >> 6) % 3;       // 0=q, 1=k, 2=v
  const int hh     = c0 / 192;

  if (region == 2) {
    #pragma unroll
    for (int j = 0; j < 4; ++j) {
      const int d = 16 * j + lc;
      #pragma unroll
      for (int i = 0; i < 4; ++i) {
        const int s0g = cRow + i * 16;
        const int bb  = s0g >> 11;
        const int s0  = s0g & 2047;
        ushort4 hv, lv;
        #pragma unroll
        for (int r = 0; r < 4; ++r) {
          ushort hi, lo; split2(acc[i][j][r], hi, lo);
          ((ushort*)&hv)[r] = hi; ((ushort*)&lv)[r] = lo;
        }
        const size_t a = ((size_t)(bb * NH + hh) * HD + d) * S_LEN + s0;
        *reinterpret_cast<ushort4*>(vTh + a) = hv;
        *reinterpret_cast<ushort4*>(vTl + a) = lv;
      }
    }
  } else {
    ushort* Oh = (region == 0) ? qTh : kTh;
    ushort* Ol = (region == 0) ? qTl : kTl;
    const float* tsc = (region == 0) ? tscq : tsck;
    #pragma unroll
    for (int j = 0; j < 4; ++j) {
      const int d  = 16 * j + lc;
      const int ii = d >> 1;
      const int im = d & 15;
      #pragma unroll
      for (int i = 0; i < 4; ++i) {
        const int s0g = cRow + i * 16;
        const int bb  = s0g >> 11;
        #pragma unroll
        for (int r = 0; r < 4; ++r) {
          const int s = (s0g + r) & 2047;
          float v = acc[i][j][r];
          float p = __shfl_xor(v, 1);
          float resv;
          if (j < 2) {  // d < 32: rotated + scaled
            const float cs  = tcs[s * 16 + ii];
            const float sn  = tsn[s * 16 + ii];
            const float scl = tsc[s * 16 + im];
            resv = ((lane & 1) ? (v * cs + p * sn) : (v * cs - p * sn)) * scl;
          } else {
            resv = v;
          }
          ushort hi, lo; split2(resv, hi, lo);
          const size_t a = ((size_t)(bb * NH + hh) * S_LEN + s) * HD + d;
          Oh[a] = hi; Ol[a] = lo;
        }
      }
    }
  }
}

// ---------------- MFMA retention: ret = (QK^T * gamma^(s-t) [s>=t]) V ----------------
__global__ __launch_bounds__(256, 2) void retention_mfma(
    const ushort* __restrict__ qTh, const ushort* __restrict__ qTl,
    const ushort* __restrict__ kTh, const ushort* __restrict__ kTl,
    const ushort* __restrict__ vTh, const ushort* __restrict__ vTl,
    float* __restrict__ ret) {
  const int sblk = blockIdx.x, h = blockIdx.y, b = blockIdx.z;
  const int tid = threadIdx.x, lane = tid & 63, w = tid >> 6;
  const int sBase = sblk << 6;
  const float l2g = log2f(1.f - exp2f(-5.f - (float)h));   // negative

  __shared__ ushort Qh[4096], Ql[4096], Kh[4096], Kl[4096],
                    Vh[4096], Vl[4096], Sh[4096], Sl[4096];

  const int l8   = lane >> 3;
  const int kswz = ((lane & 7) * 16) ^ (l8 << 4);

  auto stage16 = [&](const ushort* src, int pitch, ushort* dst, int r0) {
    #pragma unroll
    for (int c = 0; c < 2; ++c) {
      const int row = r0 + c * 8;
      const char* g = (const char*)(src + (size_t)(row + l8) * pitch) + kswz;
      __builtin_amdgcn_global_load_lds((const __attribute__((address_space(1))) void*)g,
          (__attribute__((address_space(3))) void*)((char*)dst + row * 128), 16, 0, 0);
    }
  };

  const size_t bh  = (size_t)(b * NH + h);
  const size_t bho = bh * (S_LEN * HD);

  stage16(qTh + bho + (size_t)sBase * HD, 64, Qh, w * 16);
  stage16(qTl + bho + (size_t)sBase * HD, 64, Ql, w * 16);

  const int sQr = (lane >> 4) << 2;
  float gs[4], gti[4];
  #pragma unroll
  for (int r = 0; r < 4; ++r) gs[r] = exp2f(l2g * (float)(w * 16 + sQr + r));
  #pragma unroll
  for (int j = 0; j < 4; ++j) gti[j] = exp2f(-l2g * (float)((lane & 15) + 16 * j));

  f32x4 acc[4] = {};

  const int aRow = w * 16 + (lane & 15);
  const int aOff = aRow * 128;
  const int aswz = (aRow & 7) << 4;

  for (int tblk = 0; tblk <= sblk; ++tblk) {
    const int tBase = tblk << 6;
    const int nmin  = sBase - tBase - 63;
    if (nmin > 0 && (float)nmin * l2g < -45.f) continue;
    __syncthreads();
    stage16(kTh + bho + (size_t)tBase * HD, 64,   Kh, w * 16);
    stage16(kTl + bho + (size_t)tBase * HD, 64,   Kl, w * 16);
    stage16(vTh + bho + tBase,              2048, Vh, w * 16);
    stage16(vTl + bho + tBase,              2048, Vl, w * 16);
    __syncthreads();

    f32x4 sc[4] = {};
    #pragma unroll
    for (int ks = 0; ks < 2; ++ks) {
      const int kb = ks * 64 + ((lane >> 4) << 4);
      const short8 qhf = *(const short8*)((const char*)Qh + aOff + (kb ^ aswz));
      const short8 qlf = *(const short8*)((const char*)Ql + aOff + (kb ^ aswz));
      #pragma unroll
      for (int j = 0; j < 4; ++j) {
        const int br = j * 16 + (lane & 15);
        const int bo = br * 128 + (kb ^ ((br & 7) << 4));
        const short8 khf = *(const short8*)((const char*)Kh + bo);
        const short8 klf = *(const short8*)((const char*)Kl + bo);
        sc[j] = __builtin_amdgcn_mfma_f32_16x16x32_bf16(qhf, khf, sc[j], 0, 0, 0);
        sc[j] = __builtin_amdgcn_mfma_f32_16x16x32_bf16(qhf, klf, sc[j], 0, 0, 0);
        sc[j] = __builtin_amdgcn_mfma_f32_16x16x32_bf16(qlf, khf, sc[j], 0, 0, 0);
      }
    }

    const float D0  = exp2f(l2g * (float)(sBase - tBase));
    const bool diag = (tBase == sBase);
    #pragma unroll
    for (int j = 0; j < 4; ++j) {
      const int tLoc  = (lane & 15) + 16 * j;
      const float gj  = D0 * gti[j];
      #pragma unroll
      for (int r = 0; r < 4; ++r) {
        const int sLoc = w * 16 + sQr + r;
        float dec = gj * gs[r];
        if (diag && sLoc < tLoc) dec = 0.f;
        const float v = sc[j][r] * dec;
        ushort hi, lo; split2(v, hi, lo);
        const int off = sLoc * 128 + ((tLoc * 2) ^ ((sLoc & 7) << 4));
        *(ushort*)((char*)Sh + off) = hi;
        *(ushort*)((char*)Sl + off) = lo;
      }
    }
    __syncthreads();

    #pragma unroll
    for (int ks = 0; ks < 2; ++ks) {
      const int kb = ks * 64 + ((lane >> 4) << 4);
      const short8 shf = *(const short8*)((const char*)Sh + aOff + (kb ^ aswz));
      const short8 slf = *(const short8*)((const char*)Sl + aOff + (kb ^ aswz));
      #pragma unroll
      for (int j = 0; j < 4; ++j) {
        const int br = j * 16 + (lane & 15);
        const int bo = br * 128 + (kb ^ ((br & 7) << 4));
        const short8 vhf = *(const short8*)((const char*)Vh + bo);
        const short8 vlf = *(const short8*)((const char*)Vl + bo);
        acc[j] = __builtin_amdgcn_mfma_f32_16x16x32_bf16(shf, vhf, acc[j], 0, 0, 0);
        acc[j] = __builtin_amdgcn_mfma_f32_16x16x32_bf16(shf, vlf, acc[j], 0, 0, 0);
        acc[j] = __builtin_amdgcn_mfma_f32_16x16x32_bf16(slf, vhf, acc[j], 0, 0, 0);
      }
    }
  }

  float* ob = ret + (bh * S_LEN + sBase) * HD;
  #pragma unroll
  for (int j = 0; j < 4; ++j)
    #pragma unroll
    for (int r = 0; r < 4; ++r)
      ob[(w * 16 + sQr + r) * 64 + j * 16 + (lane & 15)] = acc[j][r];
}

// ---------------- group norm + gate, emitting bf16 hi/lo ----------------
__global__ __launch_bounds__(256) void gn_kernel(const float* __restrict__ ret,
    const float* __restrict__ gm, const float* __restrict__ gn_w, const float* __restrict__ gn_b,
    ushort* __restrict__ yh, ushort* __restrict__ yl) {
  const int bh = blockIdx.x;
  const int b = bh >> 4, h = bh & 15;
  const float4* r4 = reinterpret_cast<const float4*>(ret + (size_t)bh * (S_LEN * HD));
  float s = 0.f, ss = 0.f;
  for (int i = threadIdx.x; i < S_LEN * HD / 4; i += 256) {
    const float4 v = r4[i];
    s  += v.x + v.y + v.z + v.w;
    ss += v.x*v.x + v.y*v.y + v.z*v.z + v.w*v.w;
  }
  block_reduce2(s, ss);
  const float inv  = 1.f / (float)(S_LEN * HD);
  const float mean = s * inv;
  const float var  = ss * inv - mean * mean;
  const float rstd = rsqrtf(var + EPS);
  const float a = gn_w[h] * rstd;
  const float c = gn_b[h] - mean * a;
  for (int i = threadIdx.x; i < S_LEN * HD / 4; i += 256) {
    const float4 v = r4[i];
    const int e    = i << 2;
    const int srow = e >> 6;
    const int d    = e & 63;
    const size_t oidx = (size_t)(b * S_LEN + srow) * HID + h * HD + d;
    const float4 g = *reinterpret_cast<const float4*>(gm + oidx);
    float o0 = (v.x * a + c) * g.x;
    float o1 = (v.y * a + c) * g.y;
    float o2 = (v.z * a + c) * g.z;
    float o3 = (v.w * a + c) * g.w;
    ushort4 hv, lv;
    split2(o0, hv.x, lv.x); split2(o1, hv.y, lv.y);
    split2(o2, hv.z, lv.z); split2(o3, hv.w, lv.w);
    *reinterpret_cast<ushort4*>(yh + oidx) = hv;
    *reinterpret_cast<ushort4*>(yl + oidx) = lv;
  }
}

// ---------------- launcher ----------------
extern "C" void kernel_launch(void* const* d_in, const int* in_sizes, int n_in,
                              void* d_out, int out_size, void* d_ws, size_t ws_size,
                              hipStream_t stream) {
  const float* x     = (const float*)d_in[0];
  const float* ln1_w = (const float*)d_in[1];
  const float* ln1_b = (const float*)d_in[2];
  const float* wqkv  = (const float*)d_in[3];
  const float* wg    = (const float*)d_in[4];
  const float* wo    = (const float*)d_in[5];
  const float* gn_w  = (const float*)d_in[6];
  const float* gn_b  = (const float*)d_in[7];
  const float* ln2_w = (const float*)d_in[8];
  const float* ln2_b = (const float*)d_in[9];
  const float* w1    = (const float*)d_in[10];
  const float* w1_b  = (const float*)d_in[11];
  const float* w2    = (const float*)d_in[12];
  const float* w2_b  = (const float*)d_in[13];

  char* ws = (char*)d_ws;
  ushort* wqkvgT_h = (ushort*)(ws + 0);          // 4096x1024 bf16 = 8,388,608
  ushort* wqkvgT_l = (ushort*)(ws + 8388608);    // -> 16,777,216
  ushort* woT_h   = (ushort*)(ws + 16777216);
  ushort* woT_l   = (ushort*)(ws + 18874368);
  ushort* w1T_h   = (ushort*)(ws + 20971520);
  ushort* w1T_l   = (ushort*)(ws + 23068672);
  ushort* w2T_h   = (ushort*)(ws + 25165824);
  ushort* w2T_l   = (ushort*)(ws + 27262976);
  ushort* h_hi    = (ushort*)(ws + 29360128);
  ushort* h_lo    = (ushort*)(ws + 37748736);
  float*  tcs     = (float*) (ws + 46137344);
  float*  tsn     = (float*) (ws + 46268416);
  float*  tscq    = (float*) (ws + 46399488);
  float*  tsck    = (float*) (ws + 46530560);
  ushort* qT_h    = (ushort*)(ws + 46661632);
  ushort* qT_l    = (ushort*)(ws + 55050240);
  ushort* kT_h    = (ushort*)(ws + 63438848);
  ushort* kT_l    = (ushort*)(ws + 71827456);
  ushort* vT_h    = (ushort*)(ws + 80216064);
  ushort* vT_l    = (ushort*)(ws + 88604672);
  float*  gmish   = (float*) (ws + 96993280);
  // reuses (stream-ordered):
  float*  ret     = (float*) (ws + 29360128);   // h region (dead after gemm_qkvg_rot)
  ushort* yin_h   = (ushort*)(ws + 46661632);   // qT region (dead after retention)
  ushort* yin_l   = (ushort*)(ws + 55050240);
  float*  y       = (float*) (ws + 63438848);   // kT region
  ushort* z_h     = (ushort*)(ws + 80216064);   // vT region
  ushort* z_l     = (ushort*)(ws + 88604672);
  ushort* f_h     = (ushort*)(ws + 96993280);   // gmish region (dead after gn)
  ushort* f_l     = (ushort*)(ws + 105381888);  // ends 113,770,496
  float*  out     = (float*)d_out;

  // weight transpose+split: wqkv cols 0..3071, wg cols 3072..4095 of merged B^T
  wsplit_kernel<<<dim3(3072/32, 32), 256, 0, stream>>>(wqkv, wqkvgT_h, wqkvgT_l, 3072);
  wsplit_kernel<<<dim3(1024/32, 32), 256, 0, stream>>>(wg, wqkvgT_h + 3072*1024, wqkvgT_l + 3072*1024, 1024);
  wsplit_kernel<<<dim3(1024/32, 32), 256, 0, stream>>>(wo, woT_h, woT_l, 1024);
  wsplit_kernel<<<dim3(1024/32, 32), 256, 0, stream>>>(w1, w1T_h, w1T_l, 1024);
  wsplit_kernel<<<dim3(1024/32, 32), 256, 0, stream>>>(w2, w2T_h, w2T_l, 1024);
  rot_tables_kernel<<<128, 256, 0, stream>>>(tcs, tsn, tscq, tsck);

  ln_split_kernel<<<BATCH * S_LEN, 256, 0, stream>>>(x, ln1_w, ln1_b, h_hi, h_lo);
  gemm_qkvg_rot<<<dim3(4096/128, 4096/128), 256, 0, stream>>>(h_hi, h_lo, wqkvgT_h, wqkvgT_l,
      tcs, tsn, tscq, tsck, qT_h, qT_l, kT_h, kT_l, vT_h, vT_l, gmish);
  retention_mfma<<<dim3(S_LEN/64, NH, BATCH), 256, 0, stream>>>(qT_h, qT_l, kT_h, kT_l,
      vT_h, vT_l, ret);
  gn_kernel<<<BATCH * NH, 256, 0, stream>>>(ret, gmish, gn_w, gn_b, yin_h, yin_l);
  gemm_mfma<2, 64><<<dim3(1024/64, 4096/128), 256, 0, stream>>>(yin_h, yin_l, woT_h, woT_l,
      nullptr, x, y, nullptr, nullptr, 1024, 1024);
  ln_split_kernel<<<BATCH * S_LEN, 256, 0, stream>>>(y, ln2_w, ln2_b, z_h, z_l);
  gemm_mfma<3, 64><<<dim3(1024/64, 4096/128), 256, 0, stream>>>(z_h, z_l, w1T_h, w1T_l,
      w1_b, nullptr, nullptr, f_h, f_l, 1024, 1024);
  gemm_mfma<4, 64><<<dim3(1024/64, 4096/128), 256, 0, stream>>>(f_h, f_l, w2T_h, w2T_l,
      w2_b, y, out, nullptr, nullptr, 1024, 1024);
}

// Round 8
// 550.642 us; speedup vs baseline: 3.7318x; 1.0569x over previous
//
#include <hip/hip_runtime.h>

// RetNet block: bf16x3 MFMA GEMMs + MFMA retention.
// R7: XCD-swizzled 1D grids, Q-in-registers retention (48KB LDS, 3 blocks/CU), heavy-first.
// Workspace usage: 113,770,496 bytes.

constexpr int S_LEN = 2048;
constexpr int HID   = 1024;
constexpr int NH    = 16;
constexpr int HD    = 64;
constexpr int BATCH = 2;
constexpr float EPS = 1e-5f;

using short8 = __attribute__((ext_vector_type(8))) short;
using f32x4  = __attribute__((ext_vector_type(4))) float;

// ---------------- bf16 split helpers ----------------
__device__ __forceinline__ ushort bf16rne(float x) {
  unsigned u = __float_as_uint(x);
  unsigned r = (u + 0x7fffu + ((u >> 16) & 1u)) >> 16;
  return (ushort)r;
}
__device__ __forceinline__ void split2(float x, ushort& hi, ushort& lo) {
  hi = bf16rne(x);
  float hf = __uint_as_float((unsigned)hi << 16);
  lo = bf16rne(x - hf);
}

// ---------------- reductions ----------------
__device__ __forceinline__ void block_reduce2(float& s, float& ss) {
  #pragma unroll
  for (int o = 32; o > 0; o >>= 1) {
    s  += __shfl_down(s, o, 64);
    ss += __shfl_down(ss, o, 64);
  }
  __shared__ float ls[4], lss[4];
  const int lane = threadIdx.x & 63;
  const int w    = threadIdx.x >> 6;
  if (lane == 0) { ls[w] = s; lss[w] = ss; }
  __syncthreads();
  if (threadIdx.x == 0) {
    float a = 0.f, b2 = 0.f;
    #pragma unroll
    for (int i = 0; i < 4; ++i) { a += ls[i]; b2 += lss[i]; }
    ls[0] = a; lss[0] = b2;
  }
  __syncthreads();
  s = ls[0]; ss = lss[0];
}

// ---------------- LayerNorm -> bf16 hi/lo ----------------
__global__ __launch_bounds__(256) void ln_split_kernel(const float* __restrict__ x,
    const float* __restrict__ w, const float* __restrict__ b,
    ushort* __restrict__ oh, ushort* __restrict__ ol) {
  const int row = blockIdx.x;
  const int t   = threadIdx.x;
  const float4 v = reinterpret_cast<const float4*>(x + (size_t)row * HID)[t];
  float s  = v.x + v.y + v.z + v.w;
  float ss = v.x*v.x + v.y*v.y + v.z*v.z + v.w*v.w;
  block_reduce2(s, ss);
  const float mean = s * (1.f / HID);
  const float var  = ss * (1.f / HID) - mean * mean;
  const float rstd = rsqrtf(var + EPS);
  const float4 wv = reinterpret_cast<const float4*>(w)[t];
  const float4 bv = reinterpret_cast<const float4*>(b)[t];
  float o[4];
  o[0] = (v.x - mean) * rstd * wv.x + bv.x;
  o[1] = (v.y - mean) * rstd * wv.y + bv.y;
  o[2] = (v.z - mean) * rstd * wv.z + bv.z;
  o[3] = (v.w - mean) * rstd * wv.w + bv.w;
  ushort4 hv, lv;
  split2(o[0], hv.x, lv.x); split2(o[1], hv.y, lv.y);
  split2(o[2], hv.z, lv.z); split2(o[3], hv.w, lv.w);
  *reinterpret_cast<ushort4*>(oh + (size_t)row * HID + t * 4) = hv;
  *reinterpret_cast<ushort4*>(ol + (size_t)row * HID + t * 4) = lv;
}

// ---------------- weight transpose + split: W[K][N] -> T[N][K] hi/lo ----------------
__global__ __launch_bounds__(256) void wsplit_kernel(const float* __restrict__ W,
    ushort* __restrict__ Th, ushort* __restrict__ Tl, int N) {
  __shared__ float tile[32][33];
  const int k0 = blockIdx.y * 32;
  const int n0 = blockIdx.x * 32;
  const int tx = threadIdx.x & 31, ty = threadIdx.x >> 5;
  #pragma unroll
  for (int r = 0; r < 4; ++r)
    tile[ty + 8*r][tx] = W[(size_t)(k0 + ty + 8*r) * N + n0 + tx];
  __syncthreads();
  #pragma unroll
  for (int r = 0; r < 4; ++r) {
    const int n = ty + 8*r;
    const float v = tile[tx][n];
    ushort hi, lo; split2(v, hi, lo);
    Th[(size_t)(n0 + n) * 1024 + k0 + tx] = hi;
    Tl[(size_t)(n0 + n) * 1024 + k0 + tx] = lo;
  }
}

// ---------------- rotary tables: [s][m], m=0..15 ----------------
__global__ __launch_bounds__(256) void rot_tables_kernel(float* __restrict__ tcs,
    float* __restrict__ tsn, float* __restrict__ tscq, float* __restrict__ tsck) {
  const int g = blockIdx.x * 256 + threadIdx.x;
  const int m = g & 15, s = g >> 4;
  const float invf = exp2f(-((float)(2 * m) * (1.f / 32.f)) * 13.287712379549449f);
  const float ang = (float)s * invf;
  tcs[g] = cosf(ang);
  tsn[g] = sinf(ang);
  const float p  = ((float)s - 1024.f) * (1.f / 512.f);
  const float sv = (2.f * (float)m + 12.8f) * (1.f / 44.8f);
  const float l  = log2f(sv) * p;
  tscq[g] = exp2f(l);
  tsck[g] = exp2f(-l);
}

// ---------------- epilogue helpers ----------------
__device__ __forceinline__ float mishf(float v) {
  return v * tanhf(log1pf(expf(v)));
}
__device__ __forceinline__ float geluf(float v) {
  return 0.5f * v * (1.f + erff(v * 0.7071067811865475f));
}

// ---------------- bf16x3 MFMA GEMM, tile 128 x 64, 1D grid of 512 (XCD-swizzled) ----------------
// EPI: 2 +res, 3 gelu(acc+bias)->split out, 4 acc+bias+res
template <int EPI>
__global__ __launch_bounds__(256, 3) void gemm_mfma(
    const ushort* __restrict__ Ah, const ushort* __restrict__ Al,
    const ushort* __restrict__ Bh, const ushort* __restrict__ Bl,
    const float* __restrict__ bias, const float* __restrict__ res,
    float* __restrict__ C, ushort* __restrict__ Ch, ushort* __restrict__ Cl,
    int N, int K) {
  constexpr int BN = 64;
  constexpr int MI = 2;
  __shared__ ushort sA[2][128 * 64];
  __shared__ ushort sB[2][BN * 64];
  const int D = blockIdx.x;                 // 512 blocks
  const int L = (D & 7) * 64 + (D >> 3);    // bijective XCD chunking
  const int bix = L & 15, biy = L >> 4;
  const int tid  = threadIdx.x;
  const int lane = tid & 63;
  const int w    = tid >> 6;
  const int wm   = w, wn = 0;
  const int rowBase = biy * 128;
  const int colBase = bix * BN;

  f32x4 acc[MI][4] = {};

  const int l8   = lane >> 3;
  const int kswz = ((lane & 7) * 16) ^ (l8 << 4);

  for (int k0 = 0; k0 < K; k0 += 64) {
    __syncthreads();
    #pragma unroll
    for (int c = 0; c < 4; ++c) {
      const int row = w * 32 + c * 8;
      const char* gah = (const char*)(Ah + (size_t)(rowBase + row + l8) * K + k0) + kswz;
      const char* gal = (const char*)(Al + (size_t)(rowBase + row + l8) * K + k0) + kswz;
      __builtin_amdgcn_global_load_lds((const __attribute__((address_space(1))) void*)gah,
          (__attribute__((address_space(3))) void*)((char*)sA[0] + row * 128), 16, 0, 0);
      __builtin_amdgcn_global_load_lds((const __attribute__((address_space(1))) void*)gal,
          (__attribute__((address_space(3))) void*)((char*)sA[1] + row * 128), 16, 0, 0);
    }
    #pragma unroll
    for (int c = 0; c < 2; ++c) {
      const int row = w * 16 + c * 8;
      const char* gbh = (const char*)(Bh + (size_t)(colBase + row + l8) * K + k0) + kswz;
      const char* gbl = (const char*)(Bl + (size_t)(colBase + row + l8) * K + k0) + kswz;
      __builtin_amdgcn_global_load_lds((const __attribute__((address_space(1))) void*)gbh,
          (__attribute__((address_space(3))) void*)((char*)sB[0] + row * 128), 16, 0, 0);
      __builtin_amdgcn_global_load_lds((const __attribute__((address_space(1))) void*)gbl,
          (__attribute__((address_space(3))) void*)((char*)sB[1] + row * 128), 16, 0, 0);
    }
    __syncthreads();
    #pragma unroll
    for (int kk = 0; kk < 2; ++kk) {
      const int kb = kk * 64 + ((lane >> 4) << 4);
      short8 ah[MI], al[MI], bh[4], bl[4];
      #pragma unroll
      for (int i = 0; i < MI; ++i) {
        const int row = wm * (16 * MI) + i * 16 + (lane & 15);
        const int off = row * 128 + (kb ^ ((row & 7) << 4));
        ah[i] = *(const short8*)((const char*)sA[0] + off);
        al[i] = *(const short8*)((const char*)sA[1] + off);
      }
      #pragma unroll
      for (int j = 0; j < 4; ++j) {
        const int row = wn * 64 + j * 16 + (lane & 15);
        const int off = row * 128 + (kb ^ ((row & 7) << 4));
        bh[j] = *(const short8*)((const char*)sB[0] + off);
        bl[j] = *(const short8*)((const char*)sB[1] + off);
      }
      #pragma unroll
      for (int i = 0; i < MI; ++i)
        #pragma unroll
        for (int j = 0; j < 4; ++j) {
          acc[i][j] = __builtin_amdgcn_mfma_f32_16x16x32_bf16(ah[i], bh[j], acc[i][j], 0, 0, 0);
          acc[i][j] = __builtin_amdgcn_mfma_f32_16x16x32_bf16(ah[i], bl[j], acc[i][j], 0, 0, 0);
          acc[i][j] = __builtin_amdgcn_mfma_f32_16x16x32_bf16(al[i], bh[j], acc[i][j], 0, 0, 0);
        }
    }
  }

  const int cRow = rowBase + wm * (16 * MI) + ((lane >> 4) << 2);
  const int cCol = colBase + wn * 64 + (lane & 15);
  #pragma unroll
  for (int i = 0; i < MI; ++i)
    #pragma unroll
    for (int j = 0; j < 4; ++j) {
      const int gc = cCol + j * 16;
      #pragma unroll
      for (int r = 0; r < 4; ++r) {
        const int gr = cRow + i * 16 + r;
        float v = acc[i][j][r];
        if constexpr (EPI == 2) v += res[(size_t)gr * N + gc];
        if constexpr (EPI == 3) v = geluf(v + bias[gc]);
        if constexpr (EPI == 4) v += bias[gc] + res[(size_t)gr * N + gc];
        if constexpr (EPI == 3) {
          ushort hi, lo; split2(v, hi, lo);
          Ch[(size_t)gr * N + gc] = hi;
          Cl[(size_t)gr * N + gc] = lo;
        } else {
          C[(size_t)gr * N + gc] = v;
        }
      }
    }
}

// ---------------- merged qkv+gate GEMM with fused xPos rotary + layout emit ----------------
// 1D grid of 1024 (XCD-swizzled). Cols 0..3071: q/k/v per head; cols 3072..4095: mish gate.
__global__ __launch_bounds__(256, 2) void gemm_qkvg_rot(
    const ushort* __restrict__ Ah, const ushort* __restrict__ Al,
    const ushort* __restrict__ Bh, const ushort* __restrict__ Bl,
    const float* __restrict__ tcs, const float* __restrict__ tsn,
    const float* __restrict__ tscq, const float* __restrict__ tsck,
    ushort* __restrict__ qTh, ushort* __restrict__ qTl,
    ushort* __restrict__ kTh, ushort* __restrict__ kTl,
    ushort* __restrict__ vTh, ushort* __restrict__ vTl,
    float* __restrict__ gmish) {
  const int K = 1024;
  __shared__ ushort sA[2][128 * 64];
  __shared__ ushort sB[2][128 * 64];
  const int D = blockIdx.x;                  // 1024 blocks
  const int L = (D & 7) * 128 + (D >> 3);    // bijective XCD chunking
  const int bix = L & 31, biy = L >> 5;
  const int tid  = threadIdx.x;
  const int lane = tid & 63;
  const int w    = tid >> 6;
  const int wm   = w >> 1, wn = w & 1;
  const int rowBase = biy * 128;
  const int colBase = bix * 128;

  f32x4 acc[4][4] = {};

  const int l8   = lane >> 3;
  const int kswz = ((lane & 7) * 16) ^ (l8 << 4);

  for (int k0 = 0; k0 < K; k0 += 64) {
    __syncthreads();
    #pragma unroll
    for (int c = 0; c < 4; ++c) {
      const int row = w * 32 + c * 8;
      const char* gah = (const char*)(Ah + (size_t)(rowBase + row + l8) * K + k0) + kswz;
      const char* gal = (const char*)(Al + (size_t)(rowBase + row + l8) * K + k0) + kswz;
      const char* gbh = (const char*)(Bh + (size_t)(colBase + row + l8) * K + k0) + kswz;
      const char* gbl = (const char*)(Bl + (size_t)(colBase + row + l8) * K + k0) + kswz;
      __builtin_amdgcn_global_load_lds((const __attribute__((address_space(1))) void*)gah,
          (__attribute__((address_space(3))) void*)((char*)sA[0] + row * 128), 16, 0, 0);
      __builtin_amdgcn_global_load_lds((const __attribute__((address_space(1))) void*)gal,
          (__attribute__((address_space(3))) void*)((char*)sA[1] + row * 128), 16, 0, 0);
      __builtin_amdgcn_global_load_lds((const __attribute__((address_space(1))) void*)gbh,
          (__attribute__((address_space(3))) void*)((char*)sB[0] + row * 128), 16, 0, 0);
      __builtin_amdgcn_global_load_lds((const __attribute__((address_space(1))) void*)gbl,
          (__attribute__((address_space(3))) void*)((char*)sB[1] + row * 128), 16, 0, 0);
    }
    __syncthreads();
    #pragma unroll
    for (int kk = 0; kk < 2; ++kk) {
      const int kb = kk * 64 + ((lane >> 4) << 4);
      short8 ah[4], al[4], bh[4], bl[4];
      #pragma unroll
      for (int i = 0; i < 4; ++i) {
        const int row = wm * 64 + i * 16 + (lane & 15);
        const int off = row * 128 + (kb ^ ((row & 7) << 4));
        ah[i] = *(const short8*)((const char*)sA[0] + off);
        al[i] = *(const short8*)((const char*)sA[1] + off);
      }
      #pragma unroll
      for (int j = 0; j < 4; ++j) {
        const int row = wn * 64 + j * 16 + (lane & 15);
        const int off = row * 128 + (kb ^ ((row & 7) << 4));
        bh[j] = *(const short8*)((const char*)sB[0] + off);
        bl[j] = *(const short8*)((const char*)sB[1] + off);
      }
      #pragma unroll
      for (int i = 0; i < 4; ++i)
        #pragma unroll
        for (int j = 0; j < 4; ++j) {
          acc[i][j] = __builtin_amdgcn_mfma_f32_16x16x32_bf16(ah[i], bh[j], acc[i][j], 0, 0, 0);
          acc[i][j] = __builtin_amdgcn_mfma_f32_16x16x32_bf16(ah[i], bl[j], acc[i][j], 0, 0, 0);
          acc[i][j] = __builtin_amdgcn_mfma_f32_16x16x32_bf16(al[i], bh[j], acc[i][j], 0, 0, 0);
        }
    }
  }

  // epilogue: each wave's 64-col strip is entirely q, k, v, or gate
  const int c0   = colBase + wn * 64;
  const int cRow = rowBase + wm * 64 + ((lane >> 4) << 2);
  const int lc   = lane & 15;

  if (c0 >= 3072) {              // gate region: mish -> gmish fp32 [4096][1024]
    const int gc0 = c0 - 3072;
    #pragma unroll
    for (int i = 0; i < 4; ++i)
      #pragma unroll
      for (int j = 0; j < 4; ++j) {
        const int gc = gc0 + j * 16 + lc;
        #pragma unroll
        for (int r = 0; r < 4; ++r) {
          const int gr = cRow + i * 16 + r;
          gmish[(size_t)gr * 1024 + gc] = mishf(acc[i][j][r]);
        }
      }
    return;
  }
  const int region = (c0 >> 6) % 3;       // 0=q, 1=k, 2=v
  const int hh     = c0 / 192;

  if (region == 2) {
    #pragma unroll
    for (int j = 0; j < 4; ++j) {
      const int d = 16 * j + lc;
      #pragma unroll
      for (int i = 0; i < 4; ++i) {
        const int s0g = cRow + i * 16;
        const int bb  = s0g >> 11;
        const int s0  = s0g & 2047;
        ushort4 hv, lv;
        #pragma unroll
        for (int r = 0; r < 4; ++r) {
          ushort hi, lo; split2(acc[i][j][r], hi, lo);
          ((ushort*)&hv)[r] = hi; ((ushort*)&lv)[r] = lo;
        }
        const size_t a = ((size_t)(bb * NH + hh) * HD + d) * S_LEN + s0;
        *reinterpret_cast<ushort4*>(vTh + a) = hv;
        *reinterpret_cast<ushort4*>(vTl + a) = lv;
      }
    }
  } else {
    ushort* Oh = (region == 0) ? qTh : kTh;
    ushort* Ol = (region == 0) ? qTl : kTl;
    const float* tsc = (region == 0) ? tscq : tsck;
    #pragma unroll
    for (int j = 0; j < 4; ++j) {
      const int d  = 16 * j + lc;
      const int ii = d >> 1;
      const int im = d & 15;
      #pragma unroll
      for (int i = 0; i < 4; ++i) {
        const int s0g = cRow + i * 16;
        const int bb  = s0g >> 11;
        #pragma unroll
        for (int r = 0; r < 4; ++r) {
          const int s = (s0g + r) & 2047;
          float v = acc[i][j][r];
          float p = __shfl_xor(v, 1);
          float resv;
          if (j < 2) {  // d < 32: rotated + scaled
            const float cs  = tcs[s * 16 + ii];
            const float sn  = tsn[s * 16 + ii];
            const float scl = tsc[s * 16 + im];
            resv = ((lane & 1) ? (v * cs + p * sn) : (v * cs - p * sn)) * scl;
          } else {
            resv = v;
          }
          ushort hi, lo; split2(resv, hi, lo);
          const size_t a = ((size_t)(bb * NH + hh) * S_LEN + s) * HD + d;
          Oh[a] = hi; Ol[a] = lo;
        }
      }
    }
  }
}

// ---------------- MFMA retention: 1D grid 1024, XCD-swizzled, heavy-first, Q in regs ----------------
__global__ __launch_bounds__(256, 3) void retention_mfma(
    const ushort* __restrict__ qTh, const ushort* __restrict__ qTl,
    const ushort* __restrict__ kTh, const ushort* __restrict__ kTl,
    const ushort* __restrict__ vTh, const ushort* __restrict__ vTl,
    float* __restrict__ ret) {
  const int D = blockIdx.x;
  const int L = (D & 7) * 128 + (D >> 3);    // consecutive sblk of same (b,h) share an XCD
  const int sblk = 31 - (L & 31);            // heavy blocks dispatch first
  const int h = (L >> 5) & 15;
  const int b = L >> 9;
  const int tid = threadIdx.x, lane = tid & 63, w = tid >> 6;
  const int sBase = sblk << 6;
  const float l2g = log2f(1.f - exp2f(-5.f - (float)h));   // negative

  __shared__ ushort Kh[4096], Kl[4096], Vh[4096], Vl[4096], Sh[4096], Sl[4096];

  const int l8   = lane >> 3;
  const int kswz = ((lane & 7) * 16) ^ (l8 << 4);

  auto stage16 = [&](const ushort* src, int pitch, ushort* dst, int r0) {
    #pragma unroll
    for (int c = 0; c < 2; ++c) {
      const int row = r0 + c * 8;
      const char* g = (const char*)(src + (size_t)(row + l8) * pitch) + kswz;
      __builtin_amdgcn_global_load_lds((const __attribute__((address_space(1))) void*)g,
          (__attribute__((address_space(3))) void*)((char*)dst + row * 128), 16, 0, 0);
    }
  };

  const size_t bh  = (size_t)(b * NH + h);
  const size_t bho = bh * (S_LEN * HD);

  // Q fragments in registers (loop-invariant): row = sBase + w*16 + (lane&15),
  // k-chunk ks: elements ks*32 + (lane>>4)*8 .. +8
  short8 qh[2], ql[2];
  {
    const int qrow = sBase + w * 16 + (lane & 15);
    const int d0   = (lane >> 4) << 3;
    const ushort* qb = qTh + bho + (size_t)qrow * HD;
    const ushort* qc = qTl + bho + (size_t)qrow * HD;
    qh[0] = *(const short8*)(qb + d0);
    qh[1] = *(const short8*)(qb + 32 + d0);
    ql[0] = *(const short8*)(qc + d0);
    ql[1] = *(const short8*)(qc + 32 + d0);
  }

  const int sQr = (lane >> 4) << 2;
  float gs[4], gti[4];
  #pragma unroll
  for (int r = 0; r < 4; ++r) gs[r] = exp2f(l2g * (float)(w * 16 + sQr + r));
  #pragma unroll
  for (int j = 0; j < 4; ++j) gti[j] = exp2f(-l2g * (float)((lane & 15) + 16 * j));

  f32x4 acc[4] = {};

  const int aRow = w * 16 + (lane & 15);
  const int aOff = aRow * 128;
  const int aswz = (aRow & 7) << 4;

  for (int tblk = 0; tblk <= sblk; ++tblk) {
    const int tBase = tblk << 6;
    const int nmin  = sBase - tBase - 63;
    if (nmin > 0 && (float)nmin * l2g < -45.f) continue;
    __syncthreads();
    stage16(kTh + bho + (size_t)tBase * HD, 64,   Kh, w * 16);
    stage16(kTl + bho + (size_t)tBase * HD, 64,   Kl, w * 16);
    stage16(vTh + bho + tBase,              2048, Vh, w * 16);
    stage16(vTl + bho + tBase,              2048, Vl, w * 16);
    __syncthreads();

    f32x4 sc[4] = {};
    #pragma unroll
    for (int ks = 0; ks < 2; ++ks) {
      const int kb = ks * 64 + ((lane >> 4) << 4);
      #pragma unroll
      for (int j = 0; j < 4; ++j) {
        const int br = j * 16 + (lane & 15);
        const int bo = br * 128 + (kb ^ ((br & 7) << 4));
        const short8 khf = *(const short8*)((const char*)Kh + bo);
        const short8 klf = *(const short8*)((const char*)Kl + bo);
        sc[j] = __builtin_amdgcn_mfma_f32_16x16x32_bf16(qh[ks], khf, sc[j], 0, 0, 0);
        sc[j] = __builtin_amdgcn_mfma_f32_16x16x32_bf16(qh[ks], klf, sc[j], 0, 0, 0);
        sc[j] = __builtin_amdgcn_mfma_f32_16x16x32_bf16(ql[ks], khf, sc[j], 0, 0, 0);
      }
    }

    const float D0  = exp2f(l2g * (float)(sBase - tBase));
    const bool diag = (tBase == sBase);
    #pragma unroll
    for (int j = 0; j < 4; ++j) {
      const int tLoc  = (lane & 15) + 16 * j;
      const float gj  = D0 * gti[j];
      #pragma unroll
      for (int r = 0; r < 4; ++r) {
        const int sLoc = w * 16 + sQr + r;
        float dec = gj * gs[r];
        if (diag && sLoc < tLoc) dec = 0.f;
        const float v = sc[j][r] * dec;
        ushort hi, lo; split2(v, hi, lo);
        const int off = sLoc * 128 + ((tLoc * 2) ^ ((sLoc & 7) << 4));
        *(ushort*)((char*)Sh + off) = hi;
        *(ushort*)((char*)Sl + off) = lo;
      }
    }
    __syncthreads();

    #pragma unroll
    for (int ks = 0; ks < 2; ++ks) {
      const int kb = ks * 64 + ((lane >> 4) << 4);
      const short8 shf = *(const short8*)((const char*)Sh + aOff + (kb ^ aswz));
      const short8 slf = *(const short8*)((const char*)Sl + aOff + (kb ^ aswz));
      #pragma unroll
      for (int j = 0; j < 4; ++j) {
        const int br = j * 16 + (lane & 15);
        const int bo = br * 128 + (kb ^ ((br & 7) << 4));
        const short8 vhf = *(const short8*)((const char*)Vh + bo);
        const short8 vlf = *(const short8*)((const char*)Vl + bo);
        acc[j] = __builtin_amdgcn_mfma_f32_16x16x32_bf16(shf, vhf, acc[j], 0, 0, 0);
        acc[j] = __builtin_amdgcn_mfma_f32_16x16x32_bf16(shf, vlf, acc[j], 0, 0, 0);
        acc[j] = __builtin_amdgcn_mfma_f32_16x16x32_bf16(slf, vhf, acc[j], 0, 0, 0);
      }
    }
  }

  float* ob = ret + (bh * S_LEN + sBase) * HD;
  #pragma unroll
  for (int j = 0; j < 4; ++j)
    #pragma unroll
    for (int r = 0; r < 4; ++r)
      ob[(w * 16 + sQr + r) * 64 + j * 16 + (lane & 15)] = acc[j][r];
}

// ---------------- group norm + gate, emitting bf16 hi/lo ----------------
__global__ __launch_bounds__(256) void gn_kernel(const float* __restrict__ ret,
    const float* __restrict__ gm, const float* __restrict__ gn_w, const float* __restrict__ gn_b,
    ushort* __restrict__ yh, ushort* __restrict__ yl) {
  const int bh = blockIdx.x;
  const int b = bh >> 4, h = bh & 15;
  const float4* r4 = reinterpret_cast<const float4*>(ret + (size_t)bh * (S_LEN * HD));
  float s = 0.f, ss = 0.f;
  for (int i = threadIdx.x; i < S_LEN * HD / 4; i += 256) {
    const float4 v = r4[i];
    s  += v.x + v.y + v.z + v.w;
    ss += v.x*v.x + v.y*v.y + v.z*v.z + v.w*v.w;
  }
  block_reduce2(s, ss);
  const float inv  = 1.f / (float)(S_LEN * HD);
  const float mean = s * inv;
  const float var  = ss * inv - mean * mean;
  const float rstd = rsqrtf(var + EPS);
  const float a = gn_w[h] * rstd;
  const float c = gn_b[h] - mean * a;
  for (int i = threadIdx.x; i < S_LEN * HD / 4; i += 256) {
    const float4 v = r4[i];
    const int e    = i << 2;
    const int srow = e >> 6;
    const int d    = e & 63;
    const size_t oidx = (size_t)(b * S_LEN + srow) * HID + h * HD + d;
    const float4 g = *reinterpret_cast<const float4*>(gm + oidx);
    float o0 = (v.x * a + c) * g.x;
    float o1 = (v.y * a + c) * g.y;
    float o2 = (v.z * a + c) * g.z;
    float o3 = (v.w * a + c) * g.w;
    ushort4 hv, lv;
    split2(o0, hv.x, lv.x); split2(o1, hv.y, lv.y);
    split2(o2, hv.z, lv.z); split2(o3, hv.w, lv.w);
    *reinterpret_cast<ushort4*>(yh + oidx) = hv;
    *reinterpret_cast<ushort4*>(yl + oidx) = lv;
  }
}

// ---------------- launcher ----------------
extern "C" void kernel_launch(void* const* d_in, const int* in_sizes, int n_in,
                              void* d_out, int out_size, void* d_ws, size_t ws_size,
                              hipStream_t stream) {
  const float* x     = (const float*)d_in[0];
  const float* ln1_w = (const float*)d_in[1];
  const float* ln1_b = (const float*)d_in[2];
  const float* wqkv  = (const float*)d_in[3];
  const float* wg    = (const float*)d_in[4];
  const float* wo    = (const float*)d_in[5];
  const float* gn_w  = (const float*)d_in[6];
  const float* gn_b  = (const float*)d_in[7];
  const float* ln2_w = (const float*)d_in[8];
  const float* ln2_b = (const float*)d_in[9];
  const float* w1    = (const float*)d_in[10];
  const float* w1_b  = (const float*)d_in[11];
  const float* w2    = (const float*)d_in[12];
  const float* w2_b  = (const float*)d_in[13];

  char* ws = (char*)d_ws;
  ushort* wqkvgT_h = (ushort*)(ws + 0);          // 4096x1024 bf16 = 8,388,608
  ushort* wqkvgT_l = (ushort*)(ws + 8388608);    // -> 16,777,216
  ushort* woT_h   = (ushort*)(ws + 16777216);
  ushort* woT_l   = (ushort*)(ws + 18874368);
  ushort* w1T_h   = (ushort*)(ws + 20971520);
  ushort* w1T_l   = (ushort*)(ws + 23068672);
  ushort* w2T_h   = (ushort*)(ws + 25165824);
  ushort* w2T_l   = (ushort*)(ws + 27262976);
  ushort* h_hi    = (ushort*)(ws + 29360128);
  ushort* h_lo    = (ushort*)(ws + 37748736);
  float*  tcs     = (float*) (ws + 46137344);
  float*  tsn     = (float*) (ws + 46268416);
  float*  tscq    = (float*) (ws + 46399488);
  float*  tsck    = (float*) (ws + 46530560);
  ushort* qT_h    = (ushort*)(ws + 46661632);
  ushort* qT_l    = (ushort*)(ws + 55050240);
  ushort* kT_h    = (ushort*)(ws + 63438848);
  ushort* kT_l    = (ushort*)(ws + 71827456);
  ushort* vT_h    = (ushort*)(ws + 80216064);
  ushort* vT_l    = (ushort*)(ws + 88604672);
  float*  gmish   = (float*) (ws + 96993280);
  // reuses (stream-ordered):
  float*  ret     = (float*) (ws + 29360128);   // h region (dead after gemm_qkvg_rot)
  ushort* yin_h   = (ushort*)(ws + 46661632);   // qT region (dead after retention)
  ushort* yin_l   = (ushort*)(ws + 55050240);
  float*  y       = (float*) (ws + 63438848);   // kT region
  ushort* z_h     = (ushort*)(ws + 80216064);   // vT region
  ushort* z_l     = (ushort*)(ws + 88604672);
  ushort* f_h     = (ushort*)(ws + 96993280);   // gmish region (dead after gn)
  ushort* f_l     = (ushort*)(ws + 105381888);  // ends 113,770,496
  float*  out     = (float*)d_out;

  // weight transpose+split: wqkv cols 0..3071, wg cols 3072..4095 of merged B^T
  wsplit_kernel<<<dim3(3072/32, 32), 256, 0, stream>>>(wqkv, wqkvgT_h, wqkvgT_l, 3072);
  wsplit_kernel<<<dim3(1024/32, 32), 256, 0, stream>>>(wg, wqkvgT_h + 3072*1024, wqkvgT_l + 3072*1024, 1024);
  wsplit_kernel<<<dim3(1024/32, 32), 256, 0, stream>>>(wo, woT_h, woT_l, 1024);
  wsplit_kernel<<<dim3(1024/32, 32), 256, 0, stream>>>(w1, w1T_h, w1T_l, 1024);
  wsplit_kernel<<<dim3(1024/32, 32), 256, 0, stream>>>(w2, w2T_h, w2T_l, 1024);
  rot_tables_kernel<<<128, 256, 0, stream>>>(tcs, tsn, tscq, tsck);

  ln_split_kernel<<<BATCH * S_LEN, 256, 0, stream>>>(x, ln1_w, ln1_b, h_hi, h_lo);
  gemm_qkvg_rot<<<1024, 256, 0, stream>>>(h_hi, h_lo, wqkvgT_h, wqkvgT_l,
      tcs, tsn, tscq, tsck, qT_h, qT_l, kT_h, kT_l, vT_h, vT_l, gmish);
  retention_mfma<<<1024, 256, 0, stream>>>(qT_h, qT_l, kT_h, kT_l, vT_h, vT_l, ret);
  gn_kernel<<<BATCH * NH, 256, 0, stream>>>(ret, gmish, gn_w, gn_b, yin_h, yin_l);
  gemm_mfma<2><<<512, 256, 0, stream>>>(yin_h, yin_l, woT_h, woT_l,
      nullptr, x, y, nullptr, nullptr, 1024, 1024);
  ln_split_kernel<<<BATCH * S_LEN, 256, 0, stream>>>(y, ln2_w, ln2_b, z_h, z_l);
  gemm_mfma<3><<<512, 256, 0, stream>>>(z_h, z_l, w1T_h, w1T_l,
      w1_b, nullptr, nullptr, f_h, f_l, 1024, 1024);
  gemm_mfma<4><<<512, 256, 0, stream>>>(f_h, f_l, w2T_h, w2T_l,
      w2_b, y, out, nullptr, nullptr, 1024, 1024);
}